// Round 1
// 491.309 us; speedup vs baseline: 1.2017x; 1.2017x over previous
//
#include <hip/hip_runtime.h>
#include <hip/hip_bf16.h>
#include <stdint.h>

typedef __bf16 bf16_t;
typedef __bf16 bf16x4 __attribute__((ext_vector_type(4)));
typedef __bf16 bf16x8 __attribute__((ext_vector_type(8)));
typedef float  f32x4  __attribute__((ext_vector_type(4)));

#define B_  4
#define L_  2048
#define D_  1024
#define H_  16
#define DH_ 64

// async global->LDS, 16B per lane. lds ptr is wave-uniform; HW adds lane*16.
__device__ __forceinline__ void async_load16(const bf16_t* g, bf16_t* lds) {
    __builtin_amdgcn_global_load_lds(
        (__attribute__((address_space(1))) void*)g,
        (__attribute__((address_space(3))) void*)lds, 16, 0, 0);
}

// four 1M-element weights in one launch; 262144 float4-chunks per tensor
__global__ __launch_bounds__(256) void cvt4_f32_bf16(
    const float* __restrict__ w0, const float* __restrict__ w1,
    const float* __restrict__ w2, const float* __restrict__ w3,
    bf16_t* __restrict__ o0, bf16_t* __restrict__ o1,
    bf16_t* __restrict__ o2, bf16_t* __restrict__ o3)
{
    int i = blockIdx.x * 256 + threadIdx.x;          // 0 .. 4*262144-1
    int which = i >> 18;
    int j = (i & 262143) * 4;
    const float* w = which == 0 ? w0 : which == 1 ? w1 : which == 2 ? w2 : w3;
    bf16_t*      o = which == 0 ? o0 : which == 1 ? o1 : which == 2 ? o2 : o3;
    f32x4 v = *(const f32x4*)(w + j);
    bf16x4 ov;
    ov[0] = (bf16_t)v[0]; ov[1] = (bf16_t)v[1];
    ov[2] = (bf16_t)v[2]; ov[3] = (bf16_t)v[3];
    *(bf16x4*)(o + j) = ov;
}

// three 8M-element activations (queries/keys/values) in one launch.
// 2^21 float4-chunks per tensor.
__global__ __launch_bounds__(256) void cvt3_f32_bf16(
    const float* __restrict__ a0, const float* __restrict__ a1,
    const float* __restrict__ a2,
    bf16_t* __restrict__ o0, bf16_t* __restrict__ o1, bf16_t* __restrict__ o2)
{
    int i = blockIdx.x * 256 + threadIdx.x;          // 0 .. 3*2^21-1
    int which = i >> 21;
    size_t j = (size_t)(i & ((1 << 21) - 1)) * 4;
    const float* a = which == 0 ? a0 : which == 1 ? a1 : a2;
    bf16_t*      o = which == 0 ? o0 : which == 1 ? o1 : o2;
    f32x4 v = *(const f32x4*)(a + j);
    bf16x4 ov;
    ov[0] = (bf16_t)v[0]; ov[1] = (bf16_t)v[1];
    ov[2] = (bf16_t)v[2]; ov[3] = (bf16_t)v[3];
    *(bf16x4*)(o + j) = ov;
}

// C[M,N] = A[M,K] * B[N,K]^T, bf16 in, fp32 accum. 128x128 tile, 4 waves
// (2x2 of 64x64), 16x16x32 bf16 MFMA.
// mode 0: bf16 row-major out (Cb). mode 1: bf16 scatter as Vt[B][H][DH][S]
// (Cb). mode 2: fp32 row-major out (Cf) — for the final projection.
__device__ __forceinline__ void gemm_bt_body(
    const bf16_t* __restrict__ A, const bf16_t* __restrict__ Bm,
    bf16_t* __restrict__ Cb, float* __restrict__ Cf,
    int N, int K, int mode, bf16_t* lds)
{
    const int t = threadIdx.x;
    const int w = t >> 6, l = t & 63;
    const int quad = l >> 4, l15 = l & 15;
    const int wm = w >> 1, wn = w & 1;
    const int rowBase = blockIdx.y * 128;
    const int colBase = blockIdx.x * 128;

    f32x4 acc[4][4] = {};

    for (int k0 = 0; k0 < K; k0 += 32) {
        #pragma unroll
        for (int q2 = 0; q2 < 2; ++q2) {
            int c = q2 * 256 + w * 64 + l;       // 16B chunk id, 0..511
            int r = c >> 2, kc = c & 3;          // row (64B = 4 chunks/row)
            async_load16(&A[(size_t)(rowBase + r) * K + k0 + kc * 8],
                         &lds[(q2 * 256 + w * 64) * 8]);
            async_load16(&Bm[(size_t)(colBase + r) * K + k0 + kc * 8],
                         &lds[4096 + (q2 * 256 + w * 64) * 8]);
        }
        __syncthreads();

        bf16x8 af[4], bfr[4];
        #pragma unroll
        for (int i = 0; i < 4; ++i) {
            af[i]  = *(const bf16x8*)&lds[(wm * 64 + i * 16 + l15) * 32 + quad * 8];
            bfr[i] = *(const bf16x8*)&lds[4096 + (wn * 64 + i * 16 + l15) * 32 + quad * 8];
        }
        #pragma unroll
        for (int mt = 0; mt < 4; ++mt)
            #pragma unroll
            for (int nt = 0; nt < 4; ++nt)
                acc[mt][nt] = __builtin_amdgcn_mfma_f32_16x16x32_bf16(
                    af[mt], bfr[nt], acc[mt][nt], 0, 0, 0);
        __syncthreads();
    }

    #pragma unroll
    for (int mt = 0; mt < 4; ++mt)
        #pragma unroll
        for (int nt = 0; nt < 4; ++nt)
            #pragma unroll
            for (int r = 0; r < 4; ++r) {
                int row = rowBase + wm * 64 + mt * 16 + quad * 4 + r;  // C/D: row=quad*4+reg
                int col = colBase + wn * 64 + nt * 16 + l15;           //      col=lane&15
                float v = acc[mt][nt][r];
                if (mode == 0) {
                    Cb[(size_t)row * N + col] = (bf16_t)v;
                } else if (mode == 1) {
                    int b = row >> 11, s = row & 2047;   // row = b*2048 + s
                    int h = col >> 6,  d = col & 63;     // col = h*64 + d
                    Cb[(((size_t)((b * H_ + h) * DH_ + d)) << 11) + s] = (bf16_t)v;
                } else {
                    Cf[(size_t)row * N + col] = v;
                }
            }
}

__global__ __launch_bounds__(256) void gemm_bt(
    const bf16_t* __restrict__ A, const bf16_t* __restrict__ Bm,
    bf16_t* __restrict__ Cb, float* __restrict__ Cf,
    int M, int N, int K, int mode)
{
    __shared__ __align__(16) bf16_t lds[8192];
    (void)M;
    gemm_bt_body(A, Bm, Cb, Cf, N, K, mode, lds);
}

// QKV projections fused into one launch (grid.z selects); 1536 blocks
// -> 6 blocks/CU concurrent instead of 2 (latency hiding).
__global__ __launch_bounds__(256) void gemm_qkv(
    const bf16_t* __restrict__ A0, const bf16_t* __restrict__ B0, bf16_t* __restrict__ C0,
    const bf16_t* __restrict__ A1, const bf16_t* __restrict__ B1, bf16_t* __restrict__ C1,
    const bf16_t* __restrict__ A2, const bf16_t* __restrict__ B2, bf16_t* __restrict__ C2,
    int N, int K)
{
    __shared__ __align__(16) bf16_t lds[8192];
    const int z = blockIdx.z;
    const bf16_t* A  = z == 0 ? A0 : z == 1 ? A1 : A2;
    const bf16_t* Bm = z == 0 ? B0 : z == 1 ? B1 : B2;
    bf16_t*       C  = z == 0 ? C0 : z == 1 ? C1 : C2;
    gemm_bt_body(A, Bm, C, nullptr, N, K, z == 2 ? 1 : 0, lds);
}

// ---------------------------------------------------------------------------
// Flash attention, causal. One block = (b, h, 64 Q rows); wave w owns 16 rows.
// Q:[B*L,D] (head at col h*64), K same, Vt:[B,H,DH,S]. Out: [B*L,D] bf16.
//
// All LDS tiles are 64x64 bf16 (128B rows = 8 x 16B chunks). Every tile is
// stored XOR-swizzled: chunk kc of row r lives at chunk (kc ^ (r&7)).
// global_load_lds writes linearly, so the swizzle is applied by permuting the
// per-lane GLOBAL source chunk (rule: linear dest + inverse-swz source + swz
// on read). This turns the 16-way ds_read_b128 bank conflicts into the 8-way
// BW floor (SQ_LDS_BANK_CONFLICT was ~18% of kernel cycles).
//
// Pipeline: stage(next tile) -> compute(cur) -> single __syncthreads per
// K-tile (vmcnt drain happens at the barrier, AFTER compute has covered the
// load latency). p_lds is per-wave-private: write->read needs only a
// same-wave lgkmcnt(0) fence, not a barrier.
// ---------------------------------------------------------------------------
__device__ __forceinline__ void stage_kv(
    const bf16_t* __restrict__ Kw, const bf16_t* __restrict__ Vt,
    bf16_t* kl, bf16_t* vl, int b, int h, int j0, int w, int l)
{
    #pragma unroll
    for (int q2 = 0; q2 < 2; ++q2) {
        int c  = q2 * 256 + w * 64 + l;      // 16B chunk id, 0..511
        int rr = c >> 3, kc = c & 7;         // row (128B = 8 chunks/row)
        int kcs = kc ^ (rr & 7);             // pre-swizzled global source chunk
        async_load16(&Kw[(size_t)(b * L_ + j0 + rr) * D_ + h * DH_ + kcs * 8],
                     &kl[(q2 * 256 + w * 64) * 8]);
        async_load16(&Vt[((size_t)((b * H_ + h) * DH_ + rr)) * (size_t)L_ + j0 + kcs * 8],
                     &vl[(q2 * 256 + w * 64) * 8]);
    }
}

__global__ __launch_bounds__(256) void attn_fwd(
    const bf16_t* __restrict__ Qw, const bf16_t* __restrict__ Kw,
    const bf16_t* __restrict__ Vt, bf16_t* __restrict__ Ow)
{
    __shared__ __align__(16) bf16_t k_lds[2][4096];  // 2 x 64(s) x 64(d), swz
    __shared__ __align__(16) bf16_t v_lds[2][4096];  // 2 x 64(d) x 64(s), swz
    __shared__ __align__(16) bf16_t p_lds[4096];     // 4 waves x 16 x 64, swz
    const int t = threadIdx.x;
    const int w = t >> 6, l = t & 63;
    const int quad = l >> 4, l15 = l & 15;
    const int qt = gridDim.x - 1 - blockIdx.x;    // heavy blocks first
    const int h = blockIdx.y, b = blockIdx.z;

    // Q fragments, held in registers across the whole K loop.
    // Pre-scaled by 1/sqrt(dh)=0.125 (exact in bf16: pow2 exponent shift).
    const bf16_t* qp = Qw + (size_t)(b * L_ + qt * 64 + w * 16 + l15) * D_ + h * DH_ + quad * 8;
    bf16x8 aq0 = *(const bf16x8*)qp;          // k = quad*8 + j
    bf16x8 aq1 = *(const bf16x8*)(qp + 32);   // k = 32 + quad*8 + j
    #pragma unroll
    for (int j = 0; j < 8; ++j) {
        aq0[j] = (bf16_t)((float)aq0[j] * 0.125f);
        aq1[j] = (bf16_t)((float)aq1[j] * 0.125f);
    }

    f32x4 acc[4] = {};
    float m_i[4], l_i[4];
    #pragma unroll
    for (int r = 0; r < 4; ++r) { m_i[r] = -1e30f; l_i[r] = 0.f; }

    stage_kv(Kw, Vt, k_lds[0], v_lds[0], b, h, 0, w, l);
    __syncthreads();

    int cur = 0;
    for (int jt = 0; jt <= qt; ++jt) {
        // Issue next tile's loads FIRST; latency hides under this tile's work.
        if (jt < qt)
            stage_kv(Kw, Vt, k_lds[cur ^ 1], v_lds[cur ^ 1], b, h, (jt + 1) * 64, w, l);

        // S = Q * K^T   (16x64 per wave); reads swizzled K
        f32x4 s[4] = {};
        #pragma unroll
        for (int nt = 0; nt < 4; ++nt) {
            int krow = nt * 16 + l15;
            int sx = krow & 7;
            bf16x8 bk0 = *(const bf16x8*)&k_lds[cur][krow * 64 + ((quad ^ sx) * 8)];
            bf16x8 bk1 = *(const bf16x8*)&k_lds[cur][krow * 64 + (((quad + 4) ^ sx) * 8)];
            s[nt] = __builtin_amdgcn_mfma_f32_16x16x32_bf16(aq0, bk0, s[nt], 0, 0, 0);
            s[nt] = __builtin_amdgcn_mfma_f32_16x16x32_bf16(aq1, bk1, s[nt], 0, 0, 0);
        }

        // causal mask — only the diagonal tile can be masked (wave-uniform test)
        if (jt == qt) {
            const int row0 = w * 16 + quad * 4;           // local Q row of reg r
            #pragma unroll
            for (int nt = 0; nt < 4; ++nt) {
                int col = nt * 16 + l15;                  // local K col
                #pragma unroll
                for (int r = 0; r < 4; ++r)
                    if (col > row0 + r) s[nt][r] = -1e30f;
            }
        }

        // online softmax; rows quad*4+r live in the 16-lane group sharing `quad`
        float mx[4];
        #pragma unroll
        for (int r = 0; r < 4; ++r)
            mx[r] = fmaxf(fmaxf(s[0][r], s[1][r]), fmaxf(s[2][r], s[3][r]));
        #pragma unroll
        for (int d = 1; d < 16; d <<= 1)
            #pragma unroll
            for (int r = 0; r < 4; ++r)
                mx[r] = fmaxf(mx[r], __shfl_xor(mx[r], d));

        float alpha[4], rs[4];
        #pragma unroll
        for (int r = 0; r < 4; ++r) {
            float mn = fmaxf(m_i[r], mx[r]);
            alpha[r] = __expf(m_i[r] - mn);
            m_i[r] = mn;
            rs[r] = 0.f;
        }
        #pragma unroll
        for (int nt = 0; nt < 4; ++nt)
            #pragma unroll
            for (int r = 0; r < 4; ++r) {
                float p = __expf(s[nt][r] - m_i[r]);
                s[nt][r] = p;
                rs[r] += p;
            }
        #pragma unroll
        for (int d = 1; d < 16; d <<= 1)
            #pragma unroll
            for (int r = 0; r < 4; ++r)
                rs[r] += __shfl_xor(rs[r], d);
        #pragma unroll
        for (int r = 0; r < 4; ++r) {
            l_i[r] = l_i[r] * alpha[r] + rs[r];
            acc[0][r] *= alpha[r]; acc[1][r] *= alpha[r];
            acc[2][r] *= alpha[r]; acc[3][r] *= alpha[r];
        }

        // P: C-layout -> LDS (swizzled), per-wave-private region. Cross-LANE
        // only (same wave): DS pipe is in-order per wave; lgkmcnt(0) + compiler
        // fence is sufficient, no block barrier.
        #pragma unroll
        for (int nt = 0; nt < 4; ++nt)
            #pragma unroll
            for (int r = 0; r < 4; ++r) {
                int row = quad * 4 + r;
                int col = nt * 16 + l15;
                p_lds[w * 1024 + row * 64 + (col ^ ((row & 7) << 3))] = (bf16_t)s[nt][r];
            }
        asm volatile("s_waitcnt lgkmcnt(0)" ::: "memory");

        // O += P * V  (reads swizzled P and V)
        #pragma unroll
        for (int ks = 0; ks < 2; ++ks) {
            int cp = ks * 4 + quad;
            bf16x8 ap = *(const bf16x8*)&p_lds[w * 1024 + l15 * 64 + ((cp ^ (l15 & 7)) * 8)];
            #pragma unroll
            for (int nt = 0; nt < 4; ++nt) {
                int vrow = nt * 16 + l15;
                bf16x8 bv = *(const bf16x8*)&v_lds[cur][vrow * 64 + ((cp ^ (vrow & 7)) * 8)];
                acc[nt] = __builtin_amdgcn_mfma_f32_16x16x32_bf16(ap, bv, acc[nt], 0, 0, 0);
            }
        }

        // Single barrier per K-tile: drains this iteration's async stage
        // (vmcnt) AFTER compute covered its latency, and protects buf reuse.
        __syncthreads();
        cur ^= 1;
    }

    #pragma unroll
    for (int nt = 0; nt < 4; ++nt)
        #pragma unroll
        for (int r = 0; r < 4; ++r) {
            int row = qt * 64 + w * 16 + quad * 4 + r;
            float v = acc[nt][r] / l_i[r];
            Ow[(size_t)(b * L_ + row) * D_ + h * DH_ + nt * 16 + l15] = (bf16_t)v;
        }
}

extern "C" void kernel_launch(void* const* d_in, const int* in_sizes, int n_in,
                              void* d_out, int out_size, void* d_ws, size_t ws_size,
                              hipStream_t stream)
{
    // Inputs fp32, output fp32. Compute in bf16 MFMA, final store fp32.
    const float* queries = (const float*)d_in[0];
    const float* keys    = (const float*)d_in[1];
    const float* values  = (const float*)d_in[2];
    const float* Wq = (const float*)d_in[3];
    const float* Wk = (const float*)d_in[4];
    const float* Wv = (const float*)d_in[5];
    const float* Wo = (const float*)d_in[6];
    float* out = (float*)d_out;

    const size_t SZ = (size_t)B_ * L_ * D_;   // 8,388,608
    const size_t WZ = (size_t)D_ * D_;        // 1,048,576
    bf16_t* cbuf  = (bf16_t*)d_ws;            // queries bf16 (later attn out)
    bf16_t* cWq   = cbuf + SZ;
    bf16_t* cWk   = cWq + WZ;
    bf16_t* cWv   = cWk + WZ;
    bf16_t* cWo   = cWv + WZ;
    bf16_t* q_ws  = cWo + WZ;
    bf16_t* k_ws  = q_ws + SZ;
    bf16_t* vt_ws = k_ws + SZ;                // [B,H,DH,S]
    bf16_t* a_ws  = cbuf;                     // attn out aliases cbuf (dead)

    // keys/values bf16 scratch carved from d_out (32 MiB, dead until the
    // final projection writes it).
    bf16_t* ck = (bf16_t*)d_out;
    bf16_t* cv = ck + SZ;

    dim3 gg(D_ / 128, (B_ * L_) / 128);       // (8, 64)

    cvt4_f32_bf16<<<4096, 256, 0, stream>>>(Wq, Wk, Wv, Wo, cWq, cWk, cWv, cWo);
    cvt3_f32_bf16<<<24576, 256, 0, stream>>>(queries, keys, values, cbuf, ck, cv);

    gemm_qkv<<<dim3(D_ / 128, (B_ * L_) / 128, 3), 256, 0, stream>>>(
        cbuf, cWq, q_ws,
        ck,   cWk, k_ws,
        cv,   cWv, vt_ws,
        D_, D_);

    attn_fwd<<<dim3(L_ / 64, H_, B_), 256, 0, stream>>>(q_ws, k_ws, vt_ws, a_ws);

    gemm_bt<<<gg, 256, 0, stream>>>(a_ws, cWo, nullptr, out, B_ * L_, D_, D_, 2);
}

// Round 2
// 491.037 us; speedup vs baseline: 1.2024x; 1.0006x over previous
//
#include <hip/hip_runtime.h>
#include <hip/hip_bf16.h>
#include <stdint.h>

typedef __bf16 bf16_t;
typedef __bf16 bf16x4 __attribute__((ext_vector_type(4)));
typedef __bf16 bf16x8 __attribute__((ext_vector_type(8)));
typedef float  f32x4  __attribute__((ext_vector_type(4)));

#define B_  4
#define L_  2048
#define D_  1024
#define H_  16
#define DH_ 64

// async global->LDS, 16B per lane. lds ptr is wave-uniform; HW adds lane*16.
__device__ __forceinline__ void async_load16(const bf16_t* g, bf16_t* lds) {
    __builtin_amdgcn_global_load_lds(
        (__attribute__((address_space(1))) void*)g,
        (__attribute__((address_space(3))) void*)lds, 16, 0, 0);
}

// four 1M-element weights in one launch; 262144 float4-chunks per tensor
__global__ __launch_bounds__(256) void cvt4_f32_bf16(
    const float* __restrict__ w0, const float* __restrict__ w1,
    const float* __restrict__ w2, const float* __restrict__ w3,
    bf16_t* __restrict__ o0, bf16_t* __restrict__ o1,
    bf16_t* __restrict__ o2, bf16_t* __restrict__ o3)
{
    int i = blockIdx.x * 256 + threadIdx.x;          // 0 .. 4*262144-1
    int which = i >> 18;
    int j = (i & 262143) * 4;
    const float* w = which == 0 ? w0 : which == 1 ? w1 : which == 2 ? w2 : w3;
    bf16_t*      o = which == 0 ? o0 : which == 1 ? o1 : which == 2 ? o2 : o3;
    f32x4 v = *(const f32x4*)(w + j);
    bf16x4 ov;
    ov[0] = (bf16_t)v[0]; ov[1] = (bf16_t)v[1];
    ov[2] = (bf16_t)v[2]; ov[3] = (bf16_t)v[3];
    *(bf16x4*)(o + j) = ov;
}

// three 8M-element activations (queries/keys/values) in one launch.
__global__ __launch_bounds__(256) void cvt3_f32_bf16(
    const float* __restrict__ a0, const float* __restrict__ a1,
    const float* __restrict__ a2,
    bf16_t* __restrict__ o0, bf16_t* __restrict__ o1, bf16_t* __restrict__ o2)
{
    int i = blockIdx.x * 256 + threadIdx.x;          // 0 .. 3*2^21-1
    int which = i >> 21;
    size_t j = (size_t)(i & ((1 << 21) - 1)) * 4;
    const float* a = which == 0 ? a0 : which == 1 ? a1 : a2;
    bf16_t*      o = which == 0 ? o0 : which == 1 ? o1 : o2;
    f32x4 v = *(const f32x4*)(a + j);
    bf16x4 ov;
    ov[0] = (bf16_t)v[0]; ov[1] = (bf16_t)v[1];
    ov[2] = (bf16_t)v[2]; ov[3] = (bf16_t)v[3];
    *(bf16x4*)(o + j) = ov;
}

// C[M,N] = A[M,K] * B[N,K]^T, bf16 in, fp32 accum. 128x128 tile, 4 waves
// (2x2 of 64x64), 16x16x32 bf16 MFMA.
__device__ __forceinline__ void gemm_bt_body(
    const bf16_t* __restrict__ A, const bf16_t* __restrict__ Bm,
    bf16_t* __restrict__ Cb, float* __restrict__ Cf,
    int N, int K, int mode, bf16_t* lds)
{
    const int t = threadIdx.x;
    const int w = t >> 6, l = t & 63;
    const int quad = l >> 4, l15 = l & 15;
    const int wm = w >> 1, wn = w & 1;
    const int rowBase = blockIdx.y * 128;
    const int colBase = blockIdx.x * 128;

    f32x4 acc[4][4] = {};

    for (int k0 = 0; k0 < K; k0 += 32) {
        #pragma unroll
        for (int q2 = 0; q2 < 2; ++q2) {
            int c = q2 * 256 + w * 64 + l;       // 16B chunk id, 0..511
            int r = c >> 2, kc = c & 3;          // row (64B = 4 chunks/row)
            async_load16(&A[(size_t)(rowBase + r) * K + k0 + kc * 8],
                         &lds[(q2 * 256 + w * 64) * 8]);
            async_load16(&Bm[(size_t)(colBase + r) * K + k0 + kc * 8],
                         &lds[4096 + (q2 * 256 + w * 64) * 8]);
        }
        __syncthreads();

        bf16x8 af[4], bfr[4];
        #pragma unroll
        for (int i = 0; i < 4; ++i) {
            af[i]  = *(const bf16x8*)&lds[(wm * 64 + i * 16 + l15) * 32 + quad * 8];
            bfr[i] = *(const bf16x8*)&lds[4096 + (wn * 64 + i * 16 + l15) * 32 + quad * 8];
        }
        #pragma unroll
        for (int mt = 0; mt < 4; ++mt)
            #pragma unroll
            for (int nt = 0; nt < 4; ++nt)
                acc[mt][nt] = __builtin_amdgcn_mfma_f32_16x16x32_bf16(
                    af[mt], bfr[nt], acc[mt][nt], 0, 0, 0);
        __syncthreads();
    }

    #pragma unroll
    for (int mt = 0; mt < 4; ++mt)
        #pragma unroll
        for (int nt = 0; nt < 4; ++nt)
            #pragma unroll
            for (int r = 0; r < 4; ++r) {
                int row = rowBase + wm * 64 + mt * 16 + quad * 4 + r;  // C/D: row=quad*4+reg
                int col = colBase + wn * 64 + nt * 16 + l15;           //      col=lane&15
                float v = acc[mt][nt][r];
                if (mode == 0) {
                    Cb[(size_t)row * N + col] = (bf16_t)v;
                } else if (mode == 1) {
                    int b = row >> 11, s = row & 2047;   // row = b*2048 + s
                    int h = col >> 6,  d = col & 63;     // col = h*64 + d
                    Cb[(((size_t)((b * H_ + h) * DH_ + d)) << 11) + s] = (bf16_t)v;
                } else {
                    Cf[(size_t)row * N + col] = v;
                }
            }
}

__global__ __launch_bounds__(256) void gemm_bt(
    const bf16_t* __restrict__ A, const bf16_t* __restrict__ Bm,
    bf16_t* __restrict__ Cb, float* __restrict__ Cf,
    int M, int N, int K, int mode)
{
    __shared__ __align__(16) bf16_t lds[8192];
    (void)M;
    gemm_bt_body(A, Bm, Cb, Cf, N, K, mode, lds);
}

// QKV projections fused into one launch (grid.z selects); 1536 blocks
__global__ __launch_bounds__(256) void gemm_qkv(
    const bf16_t* __restrict__ A0, const bf16_t* __restrict__ B0, bf16_t* __restrict__ C0,
    const bf16_t* __restrict__ A1, const bf16_t* __restrict__ B1, bf16_t* __restrict__ C1,
    const bf16_t* __restrict__ A2, const bf16_t* __restrict__ B2, bf16_t* __restrict__ C2,
    int N, int K)
{
    __shared__ __align__(16) bf16_t lds[8192];
    const int z = blockIdx.z;
    const bf16_t* A  = z == 0 ? A0 : z == 1 ? A1 : A2;
    const bf16_t* Bm = z == 0 ? B0 : z == 1 ? B1 : B2;
    bf16_t*       C  = z == 0 ? C0 : z == 1 ? C1 : C2;
    gemm_bt_body(A, Bm, C, nullptr, N, K, z == 2 ? 1 : 0, lds);
}

// ---------------------------------------------------------------------------
// Flash attention, causal. One block = (b, h, 128 Q rows); wave w owns 32
// rows (2 x 16-row M-fragments). K/V staged as 64x64 XOR-swizzled LDS tiles
// (chunk kc of row r at kc^(r&7); swizzle applied on the GLOBAL source since
// global_load_lds writes linearly). K/V fragment reads are shared across the
// 2 M-fragments -> LDS read traffic per unit work -40% vs QBLK=64; staging
// bytes and barriers per unit work halve.
//
// Online softmax with defer-max (T13): skip the alpha-rescale whenever the
// tile max doesn't exceed the running max by >8 (scores here have tiny
// variance, so this triggers ~always after the first tile). P bounded by e^8
// in f32->bf16: safe.
//
// Pipeline: stage(next) -> compute(cur) -> one __syncthreads per K-tile.
// p_lds is per-wave-private: write->read fenced by same-wave lgkmcnt(0).
// Waves whose 32 rows are entirely above the current K-tile (fully masked)
// skip compute but still stage + barrier.
// ---------------------------------------------------------------------------
__device__ __forceinline__ void stage_kv(
    const bf16_t* __restrict__ Kw, const bf16_t* __restrict__ Vt,
    bf16_t* kl, bf16_t* vl, int b, int h, int j0, int w, int l)
{
    #pragma unroll
    for (int q2 = 0; q2 < 2; ++q2) {
        int c  = q2 * 256 + w * 64 + l;      // 16B chunk id, 0..511
        int rr = c >> 3, kc = c & 7;         // row (128B = 8 chunks/row)
        int kcs = kc ^ (rr & 7);             // pre-swizzled global source chunk
        async_load16(&Kw[(size_t)(b * L_ + j0 + rr) * D_ + h * DH_ + kcs * 8],
                     &kl[(q2 * 256 + w * 64) * 8]);
        async_load16(&Vt[((size_t)((b * H_ + h) * DH_ + rr)) * (size_t)L_ + j0 + kcs * 8],
                     &vl[(q2 * 256 + w * 64) * 8]);
    }
}

__global__ __launch_bounds__(256) void attn_fwd(
    const bf16_t* __restrict__ Qw, const bf16_t* __restrict__ Kw,
    const bf16_t* __restrict__ Vt, bf16_t* __restrict__ Ow)
{
    __shared__ __align__(16) bf16_t k_lds[2][4096];  // 2 x 64(s) x 64(d), swz
    __shared__ __align__(16) bf16_t v_lds[2][4096];  // 2 x 64(d) x 64(s), swz
    __shared__ __align__(16) bf16_t p_lds[8192];     // 4 waves x 32 x 64, swz
    const int t = threadIdx.x;
    const int w = t >> 6, l = t & 63;
    const int quad = l >> 4, l15 = l & 15;
    const int qt = gridDim.x - 1 - blockIdx.x;    // heavy blocks first
    const int h = blockIdx.y, b = blockIdx.z;

    // Q fragments (2 M-tiles x 2 k-slices), pre-scaled by 1/8 (exact in bf16).
    bf16x8 aq[2][2];
    #pragma unroll
    for (int mt = 0; mt < 2; ++mt) {
        const bf16_t* qp = Qw + (size_t)(b * L_ + qt * 128 + w * 32 + mt * 16 + l15) * D_
                              + h * DH_ + quad * 8;
        aq[mt][0] = *(const bf16x8*)qp;
        aq[mt][1] = *(const bf16x8*)(qp + 32);
        #pragma unroll
        for (int j = 0; j < 8; ++j) {
            aq[mt][0][j] = (bf16_t)((float)aq[mt][0][j] * 0.125f);
            aq[mt][1][j] = (bf16_t)((float)aq[mt][1][j] * 0.125f);
        }
    }

    f32x4 acc[2][4] = {};
    float m_i[2][4], l_i[2][4];
    #pragma unroll
    for (int mt = 0; mt < 2; ++mt)
        #pragma unroll
        for (int r = 0; r < 4; ++r) { m_i[mt][r] = -1e30f; l_i[mt][r] = 0.f; }

    stage_kv(Kw, Vt, k_lds[0], v_lds[0], b, h, 0, w, l);
    __syncthreads();

    const int nkt  = 2 * qt + 2;              // # of 64-wide K tiles
    const int wmax = qt * 128 + w * 32 + 31;  // this wave's max Q row
    int cur = 0;
    for (int jt = 0; jt < nkt; ++jt) {
        if (jt + 1 < nkt)
            stage_kv(Kw, Vt, k_lds[cur ^ 1], v_lds[cur ^ 1], b, h, (jt + 1) * 64, w, l);

        const int j0 = jt * 64;
        if (j0 <= wmax) {                     // wave-uniform: skip fully-masked tile
            // S = Q * K^T ; K frags shared across both M-fragments
            f32x4 s[2][4];
            #pragma unroll
            for (int mt = 0; mt < 2; ++mt)
                #pragma unroll
                for (int nt = 0; nt < 4; ++nt) s[mt][nt] = (f32x4){0.f, 0.f, 0.f, 0.f};
            #pragma unroll
            for (int nt = 0; nt < 4; ++nt) {
                int krow = nt * 16 + l15;
                int sx = krow & 7;
                bf16x8 bk0 = *(const bf16x8*)&k_lds[cur][krow * 64 + ((quad ^ sx) * 8)];
                bf16x8 bk1 = *(const bf16x8*)&k_lds[cur][krow * 64 + (((quad + 4) ^ sx) * 8)];
                s[0][nt] = __builtin_amdgcn_mfma_f32_16x16x32_bf16(aq[0][0], bk0, s[0][nt], 0, 0, 0);
                s[0][nt] = __builtin_amdgcn_mfma_f32_16x16x32_bf16(aq[0][1], bk1, s[0][nt], 0, 0, 0);
                s[1][nt] = __builtin_amdgcn_mfma_f32_16x16x32_bf16(aq[1][0], bk0, s[1][nt], 0, 0, 0);
                s[1][nt] = __builtin_amdgcn_mfma_f32_16x16x32_bf16(aq[1][1], bk1, s[1][nt], 0, 0, 0);
            }

            // causal mask — only the last two K-tiles can straddle the diagonal
            if (jt >= 2 * qt) {
                #pragma unroll
                for (int mt = 0; mt < 2; ++mt) {
                    const int row0 = qt * 128 + w * 32 + mt * 16 + quad * 4;
                    #pragma unroll
                    for (int nt = 0; nt < 4; ++nt) {
                        int col = j0 + nt * 16 + l15;
                        #pragma unroll
                        for (int r = 0; r < 4; ++r)
                            if (col > row0 + r) s[mt][nt][r] = -1e30f;
                    }
                }
            }

            // online softmax (two independent M-fragments -> 2x ILP)
            float mx[2][4];
            #pragma unroll
            for (int mt = 0; mt < 2; ++mt)
                #pragma unroll
                for (int r = 0; r < 4; ++r)
                    mx[mt][r] = fmaxf(fmaxf(s[mt][0][r], s[mt][1][r]),
                                      fmaxf(s[mt][2][r], s[mt][3][r]));
            #pragma unroll
            for (int d = 1; d < 16; d <<= 1)
                #pragma unroll
                for (int mt = 0; mt < 2; ++mt)
                    #pragma unroll
                    for (int r = 0; r < 4; ++r)
                        mx[mt][r] = fmaxf(mx[mt][r], __shfl_xor(mx[mt][r], d));

            // defer-max: skip rescale unless the max actually grew (>8)
            int small = 1;
            #pragma unroll
            for (int mt = 0; mt < 2; ++mt)
                #pragma unroll
                for (int r = 0; r < 4; ++r)
                    small &= (mx[mt][r] <= m_i[mt][r] + 8.f);
            if (!__all(small)) {
                #pragma unroll
                for (int mt = 0; mt < 2; ++mt)
                    #pragma unroll
                    for (int r = 0; r < 4; ++r) {
                        float mn = fmaxf(m_i[mt][r], mx[mt][r]);
                        float alpha = __expf(m_i[mt][r] - mn);
                        m_i[mt][r] = mn;
                        l_i[mt][r] *= alpha;
                        acc[mt][0][r] *= alpha; acc[mt][1][r] *= alpha;
                        acc[mt][2][r] *= alpha; acc[mt][3][r] *= alpha;
                    }
            }

            float rs[2][4] = {};
            #pragma unroll
            for (int mt = 0; mt < 2; ++mt)
                #pragma unroll
                for (int nt = 0; nt < 4; ++nt)
                    #pragma unroll
                    for (int r = 0; r < 4; ++r) {
                        float p = __expf(s[mt][nt][r] - m_i[mt][r]);
                        s[mt][nt][r] = p;
                        rs[mt][r] += p;
                    }
            #pragma unroll
            for (int d = 1; d < 16; d <<= 1)
                #pragma unroll
                for (int mt = 0; mt < 2; ++mt)
                    #pragma unroll
                    for (int r = 0; r < 4; ++r)
                        rs[mt][r] += __shfl_xor(rs[mt][r], d);
            #pragma unroll
            for (int mt = 0; mt < 2; ++mt)
                #pragma unroll
                for (int r = 0; r < 4; ++r)
                    l_i[mt][r] += rs[mt][r];

            // P: C-layout -> per-wave LDS region (swizzled), same-wave fence
            #pragma unroll
            for (int mt = 0; mt < 2; ++mt)
                #pragma unroll
                for (int nt = 0; nt < 4; ++nt)
                    #pragma unroll
                    for (int r = 0; r < 4; ++r) {
                        int row = mt * 16 + quad * 4 + r;
                        int col = nt * 16 + l15;
                        p_lds[w * 2048 + row * 64 + (col ^ ((row & 7) << 3))] =
                            (bf16_t)s[mt][nt][r];
                    }
            asm volatile("s_waitcnt lgkmcnt(0)" ::: "memory");

            // O += P * V ; V frags shared across both M-fragments
            #pragma unroll
            for (int ks = 0; ks < 2; ++ks) {
                int cp = ks * 4 + quad;
                bf16x8 ap0 = *(const bf16x8*)
                    &p_lds[w * 2048 + (l15) * 64 + ((cp ^ (l15 & 7)) * 8)];
                bf16x8 ap1 = *(const bf16x8*)
                    &p_lds[w * 2048 + (16 + l15) * 64 + ((cp ^ (l15 & 7)) * 8)];
                #pragma unroll
                for (int nt = 0; nt < 4; ++nt) {
                    int vrow = nt * 16 + l15;
                    bf16x8 bv = *(const bf16x8*)
                        &v_lds[cur][vrow * 64 + ((cp ^ (vrow & 7)) * 8)];
                    acc[0][nt] = __builtin_amdgcn_mfma_f32_16x16x32_bf16(ap0, bv, acc[0][nt], 0, 0, 0);
                    acc[1][nt] = __builtin_amdgcn_mfma_f32_16x16x32_bf16(ap1, bv, acc[1][nt], 0, 0, 0);
                }
            }
        }

        __syncthreads();   // drains this iter's async stage; protects buf reuse
        cur ^= 1;
    }

    #pragma unroll
    for (int mt = 0; mt < 2; ++mt)
        #pragma unroll
        for (int nt = 0; nt < 4; ++nt)
            #pragma unroll
            for (int r = 0; r < 4; ++r) {
                int row = qt * 128 + w * 32 + mt * 16 + quad * 4 + r;
                float v = acc[mt][nt][r] / l_i[mt][r];
                Ow[(size_t)(b * L_ + row) * D_ + h * DH_ + nt * 16 + l15] = (bf16_t)v;
            }
}

extern "C" void kernel_launch(void* const* d_in, const int* in_sizes, int n_in,
                              void* d_out, int out_size, void* d_ws, size_t ws_size,
                              hipStream_t stream)
{
    // Inputs fp32, output fp32. Compute in bf16 MFMA, final store fp32.
    const float* queries = (const float*)d_in[0];
    const float* keys    = (const float*)d_in[1];
    const float* values  = (const float*)d_in[2];
    const float* Wq = (const float*)d_in[3];
    const float* Wk = (const float*)d_in[4];
    const float* Wv = (const float*)d_in[5];
    const float* Wo = (const float*)d_in[6];
    float* out = (float*)d_out;

    const size_t SZ = (size_t)B_ * L_ * D_;   // 8,388,608
    const size_t WZ = (size_t)D_ * D_;        // 1,048,576
    bf16_t* cbuf  = (bf16_t*)d_ws;            // queries bf16 (later attn out)
    bf16_t* cWq   = cbuf + SZ;
    bf16_t* cWk   = cWq + WZ;
    bf16_t* cWv   = cWk + WZ;
    bf16_t* cWo   = cWv + WZ;
    bf16_t* q_ws  = cWo + WZ;
    bf16_t* k_ws  = q_ws + SZ;
    bf16_t* vt_ws = k_ws + SZ;                // [B,H,DH,S]
    bf16_t* a_ws  = cbuf;                     // attn out aliases cbuf (dead)

    // keys/values bf16 scratch carved from d_out (dead until final GEMM).
    bf16_t* ck = (bf16_t*)d_out;
    bf16_t* cv = ck + SZ;

    dim3 gg(D_ / 128, (B_ * L_) / 128);       // (8, 64)

    cvt4_f32_bf16<<<4096, 256, 0, stream>>>(Wq, Wk, Wv, Wo, cWq, cWk, cWv, cWo);
    cvt3_f32_bf16<<<24576, 256, 0, stream>>>(queries, keys, values, cbuf, ck, cv);

    gemm_qkv<<<dim3(D_ / 128, (B_ * L_) / 128, 3), 256, 0, stream>>>(
        cbuf, cWq, q_ws,
        ck,   cWk, k_ws,
        cv,   cWv, vt_ws,
        D_, D_);

    attn_fwd<<<dim3(L_ / 128, H_, B_), 256, 0, stream>>>(q_ws, k_ws, vt_ws, a_ws);

    gemm_bt<<<gg, 256, 0, stream>>>(a_ws, cWo, nullptr, out, B_ * L_, D_, D_, 2);
}

// Round 4
// 422.465 us; speedup vs baseline: 1.3976x; 1.1623x over previous
//
#include <hip/hip_runtime.h>
#include <hip/hip_bf16.h>
#include <stdint.h>

typedef __bf16 bf16_t;
typedef __bf16 bf16x4 __attribute__((ext_vector_type(4)));
typedef __bf16 bf16x8 __attribute__((ext_vector_type(8)));
typedef float  f32x4  __attribute__((ext_vector_type(4)));
typedef float  f32x16 __attribute__((ext_vector_type(16)));
typedef unsigned int u32;

#define B_  4
#define L_  2048
#define D_  1024
#define H_  16
#define DH_ 64

// async global->LDS, 16B per lane. lds ptr is wave-uniform; HW adds lane*16.
__device__ __forceinline__ void async_load16(const bf16_t* g, bf16_t* lds) {
    __builtin_amdgcn_global_load_lds(
        (__attribute__((address_space(1))) void*)g,
        (__attribute__((address_space(3))) void*)lds, 16, 0, 0);
}

// four 1M-element weights in one launch; 262144 float4-chunks per tensor
__global__ __launch_bounds__(256) void cvt4_f32_bf16(
    const float* __restrict__ w0, const float* __restrict__ w1,
    const float* __restrict__ w2, const float* __restrict__ w3,
    bf16_t* __restrict__ o0, bf16_t* __restrict__ o1,
    bf16_t* __restrict__ o2, bf16_t* __restrict__ o3)
{
    int i = blockIdx.x * 256 + threadIdx.x;          // 0 .. 4*262144-1
    int which = i >> 18;
    int j = (i & 262143) * 4;
    const float* w = which == 0 ? w0 : which == 1 ? w1 : which == 2 ? w2 : w3;
    bf16_t*      o = which == 0 ? o0 : which == 1 ? o1 : which == 2 ? o2 : o3;
    f32x4 v = *(const f32x4*)(w + j);
    bf16x4 ov;
    ov[0] = (bf16_t)v[0]; ov[1] = (bf16_t)v[1];
    ov[2] = (bf16_t)v[2]; ov[3] = (bf16_t)v[3];
    *(bf16x4*)(o + j) = ov;
}

// three 8M-element activations (queries/keys/values) in one launch.
__global__ __launch_bounds__(256) void cvt3_f32_bf16(
    const float* __restrict__ a0, const float* __restrict__ a1,
    const float* __restrict__ a2,
    bf16_t* __restrict__ o0, bf16_t* __restrict__ o1, bf16_t* __restrict__ o2)
{
    int i = blockIdx.x * 256 + threadIdx.x;          // 0 .. 3*2^21-1
    int which = i >> 21;
    size_t j = (size_t)(i & ((1 << 21) - 1)) * 4;
    const float* a = which == 0 ? a0 : which == 1 ? a1 : a2;
    bf16_t*      o = which == 0 ? o0 : which == 1 ? o1 : o2;
    f32x4 v = *(const f32x4*)(a + j);
    bf16x4 ov;
    ov[0] = (bf16_t)v[0]; ov[1] = (bf16_t)v[1];
    ov[2] = (bf16_t)v[2]; ov[3] = (bf16_t)v[3];
    *(bf16x4*)(o + j) = ov;
}

// C[M,N] = A[M,K] * B[N,K]^T, bf16 in, fp32 accum. 128x128 tile, 4 waves
// (2x2 of 64x64), 16x16x32 bf16 MFMA.
__device__ __forceinline__ void gemm_bt_body(
    const bf16_t* __restrict__ A, const bf16_t* __restrict__ Bm,
    bf16_t* __restrict__ Cb, float* __restrict__ Cf,
    int N, int K, int mode, bf16_t* lds)
{
    const int t = threadIdx.x;
    const int w = t >> 6, l = t & 63;
    const int quad = l >> 4, l15 = l & 15;
    const int wm = w >> 1, wn = w & 1;
    const int rowBase = blockIdx.y * 128;
    const int colBase = blockIdx.x * 128;

    f32x4 acc[4][4] = {};

    for (int k0 = 0; k0 < K; k0 += 32) {
        #pragma unroll
        for (int q2 = 0; q2 < 2; ++q2) {
            int c = q2 * 256 + w * 64 + l;       // 16B chunk id, 0..511
            int r = c >> 2, kc = c & 3;          // row (64B = 4 chunks/row)
            async_load16(&A[(size_t)(rowBase + r) * K + k0 + kc * 8],
                         &lds[(q2 * 256 + w * 64) * 8]);
            async_load16(&Bm[(size_t)(colBase + r) * K + k0 + kc * 8],
                         &lds[4096 + (q2 * 256 + w * 64) * 8]);
        }
        __syncthreads();

        bf16x8 af[4], bfr[4];
        #pragma unroll
        for (int i = 0; i < 4; ++i) {
            af[i]  = *(const bf16x8*)&lds[(wm * 64 + i * 16 + l15) * 32 + quad * 8];
            bfr[i] = *(const bf16x8*)&lds[4096 + (wn * 64 + i * 16 + l15) * 32 + quad * 8];
        }
        #pragma unroll
        for (int mt = 0; mt < 4; ++mt)
            #pragma unroll
            for (int nt = 0; nt < 4; ++nt)
                acc[mt][nt] = __builtin_amdgcn_mfma_f32_16x16x32_bf16(
                    af[mt], bfr[nt], acc[mt][nt], 0, 0, 0);
        __syncthreads();
    }

    #pragma unroll
    for (int mt = 0; mt < 4; ++mt)
        #pragma unroll
        for (int nt = 0; nt < 4; ++nt)
            #pragma unroll
            for (int r = 0; r < 4; ++r) {
                int row = rowBase + wm * 64 + mt * 16 + quad * 4 + r;  // C/D: row=quad*4+reg
                int col = colBase + wn * 64 + nt * 16 + l15;           //      col=lane&15
                float v = acc[mt][nt][r];
                if (mode == 0) {
                    Cb[(size_t)row * N + col] = (bf16_t)v;
                } else if (mode == 1) {
                    int b = row >> 11, s = row & 2047;   // row = b*2048 + s
                    int h = col >> 6,  d = col & 63;     // col = h*64 + d
                    Cb[(((size_t)((b * H_ + h) * DH_ + d)) << 11) + s] = (bf16_t)v;
                } else {
                    Cf[(size_t)row * N + col] = v;
                }
            }
}

__global__ __launch_bounds__(256) void gemm_bt(
    const bf16_t* __restrict__ A, const bf16_t* __restrict__ Bm,
    bf16_t* __restrict__ Cb, float* __restrict__ Cf,
    int M, int N, int K, int mode)
{
    __shared__ __align__(16) bf16_t lds[8192];
    (void)M;
    gemm_bt_body(A, Bm, Cb, Cf, N, K, mode, lds);
}

// QKV projections fused into one launch (grid.z selects); 1536 blocks
__global__ __launch_bounds__(256) void gemm_qkv(
    const bf16_t* __restrict__ A0, const bf16_t* __restrict__ B0, bf16_t* __restrict__ C0,
    const bf16_t* __restrict__ A1, const bf16_t* __restrict__ B1, bf16_t* __restrict__ C1,
    const bf16_t* __restrict__ A2, const bf16_t* __restrict__ B2, bf16_t* __restrict__ C2,
    int N, int K)
{
    __shared__ __align__(16) bf16_t lds[8192];
    const int z = blockIdx.z;
    const bf16_t* A  = z == 0 ? A0 : z == 1 ? A1 : A2;
    const bf16_t* Bm = z == 0 ? B0 : z == 1 ? B1 : B2;
    bf16_t*       C  = z == 0 ? C0 : z == 1 ? C1 : C2;
    gemm_bt_body(A, Bm, C, nullptr, N, K, z == 2 ? 1 : 0, lds);
}

// ---------------------------------------------------------------------------
// Flash attention, causal — swapped-QK^T 32x32x16 structure.
//
// One block = (b, h, 128 Q rows); 4 waves, wave owns 32 rows. KVBLK=64.
// QK^T computes mfma(A=K, B=Q): C col=lane&31 = QUERY q, row = key. Lane
// (l31, hi) holds, for query q=l31, the 32 keys {(reg&3)+8*(reg>>2)+4*hi}
// of each 32-key block; partner lane l^32 holds the complementary 32.
// Softmax fully in-register: 31-op local max/sum tree + ONE __shfl_xor(.,32)
// combine. No p_lds round trip, no shuffle cascades.
//
// P -> PV A-fragments: pa[ks][j] must equal P[q][ks*16 + hi*8 + j].
// Mapping (derived from C-layout row=(reg&3)+8*(reg>>2)+4*hi, both checked):
//   hi=0: words = [own r0r1, own r2r3, partner r0r1, partner r2r3]
//   hi=1: words = [partner r4r5, partner r6r7, own r4r5, own r6r7]
// where rN = exp'd reg N of the ks-th 8-reg group. Exchange via 2
// __shfl_xor(.,32) of the half the partner needs (hi=0 sends r4-7, hi=1
// sends r0-3) + hi-selects. Packing via scalar bf16 casts (compiler packs).
//
// Layout facts (guide-verified m74/m101) for 32x32x16_bf16:
//   A: row=lane&31, k=(lane>>5)*8+j ; B: col=lane&31, k=(lane>>5)*8+j
//   C: col=lane&31, row=(reg&3)+8*(reg>>2)+4*(lane>>5)
//
// K/V LDS tiles 64x64 bf16, XOR-swizzled (chunk kc of row r at kc^(r&7),
// applied on the GLOBAL source; global_load_lds writes linearly).
// m/l are one scalar per lane (per query, identical across the hi-halves).
// Rescale (rare, defer-max thr=8) and final 1/l redistribute query-indexed
// scalars to the row-indexed acc layout via a 128B per-wave LDS scratch.
// ---------------------------------------------------------------------------
__device__ __forceinline__ u32 pack2(float a, float b) {
    union { u32 u; bf16_t h[2]; } p;
    p.h[0] = (bf16_t)a; p.h[1] = (bf16_t)b;
    return p.u;
}

__device__ __forceinline__ void stage_kv(
    const bf16_t* __restrict__ Kw, const bf16_t* __restrict__ Vt,
    bf16_t* kl, bf16_t* vl, int b, int h, int j0, int w, int l)
{
    #pragma unroll
    for (int q2 = 0; q2 < 2; ++q2) {
        int c  = q2 * 256 + w * 64 + l;      // 16B chunk id, 0..511
        int rr = c >> 3, kc = c & 7;         // row (128B = 8 chunks/row)
        int kcs = kc ^ (rr & 7);             // pre-swizzled global source chunk
        async_load16(&Kw[(size_t)(b * L_ + j0 + rr) * D_ + h * DH_ + kcs * 8],
                     &kl[(q2 * 256 + w * 64) * 8]);
        async_load16(&Vt[((size_t)((b * H_ + h) * DH_ + rr)) * (size_t)L_ + j0 + kcs * 8],
                     &vl[(q2 * 256 + w * 64) * 8]);
    }
}

__global__ __launch_bounds__(256) void attn_fwd(
    const bf16_t* __restrict__ Qw, const bf16_t* __restrict__ Kw,
    const bf16_t* __restrict__ Vt, bf16_t* __restrict__ Ow)
{
    __shared__ __align__(16) bf16_t k_lds[2][4096];  // 2 x 64(s) x 64(d), swz
    __shared__ __align__(16) bf16_t v_lds[2][4096];  // 2 x 64(d) x 64(s), swz
    __shared__ float l_scr[4][32];                   // per-wave redistribute

    const int t = threadIdx.x;
    const int w = t >> 6, l = t & 63;
    const int l31 = l & 31, hi = l >> 5;
    const int qt = gridDim.x - 1 - blockIdx.x;    // heavy blocks first
    const int h = blockIdx.y, b = blockIdx.z;

    const int qrow = qt * 128 + w * 32 + l31;     // this lane's query

    // Q fragments (B-operand): bq[kd][j] = Q[qrow][kd*16 + hi*8 + j] * 0.125
    bf16x8 bq[4];
    {
        const bf16_t* qp = Qw + (size_t)(b * L_ + qrow) * D_ + h * DH_ + hi * 8;
        #pragma unroll
        for (int kd = 0; kd < 4; ++kd) {
            bq[kd] = *(const bf16x8*)(qp + kd * 16);
            #pragma unroll
            for (int j = 0; j < 8; ++j)
                bq[kd][j] = (bf16_t)((float)bq[kd][j] * 0.125f);
        }
    }

    f32x16 acc0 = {}, acc1 = {};   // O: col=lane&31=d (acc1: d+32), row=query
    float m_i = -1e30f, l_i = 0.f;

    stage_kv(Kw, Vt, k_lds[0], v_lds[0], b, h, 0, w, l);
    __syncthreads();

    const int nkt  = 2 * qt + 2;
    const int wmax = qt * 128 + w * 32 + 31;
    int cur = 0;
    for (int jt = 0; jt < nkt; ++jt) {
        if (jt + 1 < nkt)
            stage_kv(Kw, Vt, k_lds[cur ^ 1], v_lds[cur ^ 1], b, h, (jt + 1) * 64, w, l);

        const int j0 = jt * 64;
        if (j0 <= wmax) {                 // wave-uniform: skip fully-masked tile
            // S^T = K * Q^T : s0 = keys 0..31, s1 = keys 32..63 (local)
            f32x16 s0 = {}, s1 = {};
            #pragma unroll
            for (int kd = 0; kd < 4; ++kd) {
                int sw = ((kd * 2 + hi) ^ (l31 & 7)) * 8;   // same for both rows
                bf16x8 ak0 = *(const bf16x8*)&k_lds[cur][l31 * 64 + sw];
                bf16x8 ak1 = *(const bf16x8*)&k_lds[cur][(32 + l31) * 64 + sw];
                s0 = __builtin_amdgcn_mfma_f32_32x32x16_bf16(ak0, bq[kd], s0, 0, 0, 0);
                s1 = __builtin_amdgcn_mfma_f32_32x32x16_bf16(ak1, bq[kd], s1, 0, 0, 0);
            }

            // causal mask — only the last two K-tiles can straddle the diagonal
            if (jt >= 2 * qt) {
                #pragma unroll
                for (int reg = 0; reg < 16; ++reg) {
                    int row = (reg & 3) + 8 * (reg >> 2) + 4 * hi;  // local key
                    if (j0 + row > qrow)      s0[reg] = -1e30f;
                    if (j0 + 32 + row > qrow) s1[reg] = -1e30f;
                }
            }

            // row max: local tree over 32 values + one cross-half combine
            float mt_[16];
            #pragma unroll
            for (int r = 0; r < 16; ++r) mt_[r] = fmaxf(s0[r], s1[r]);
            #pragma unroll
            for (int st = 8; st > 0; st >>= 1)
                #pragma unroll
                for (int r = 0; r < st; ++r) mt_[r] = fmaxf(mt_[r], mt_[r + st]);
            float mx = fmaxf(mt_[0], __shfl_xor(mt_[0], 32));

            // defer-max (T13): full rescale only when the max actually grew
            int grew = !(mx <= m_i + 8.f);
            if (__any(grew)) {
                float mn = fmaxf(m_i, mx);
                float alpha = __expf(m_i - mn);
                m_i = mn; l_i *= alpha;
                // redistribute alpha (query-indexed) to acc rows via scratch
                l_scr[w][l31] = alpha;     // both hi-halves write same value
                asm volatile("s_waitcnt lgkmcnt(0)" ::: "memory");
                #pragma unroll
                for (int reg = 0; reg < 16; ++reg) {
                    int row = (reg & 3) + 8 * (reg >> 2) + 4 * hi;
                    float a2 = l_scr[w][row];          // broadcast read
                    acc0[reg] *= a2; acc1[reg] *= a2;
                }
            }

            // p = exp(s - m) in place; row sum tree + cross-half combine
            #pragma unroll
            for (int r = 0; r < 16; ++r) s0[r] = __expf(s0[r] - m_i);
            #pragma unroll
            for (int r = 0; r < 16; ++r) s1[r] = __expf(s1[r] - m_i);
            float st_[16];
            #pragma unroll
            for (int r = 0; r < 16; ++r) st_[r] = s0[r] + s1[r];
            #pragma unroll
            for (int st = 8; st > 0; st >>= 1)
                #pragma unroll
                for (int r = 0; r < st; ++r) st_[r] += st_[r + st];
            l_i += st_[0] + __shfl_xor(st_[0], 32);

            // PV: per ks (16-key slice), build A-fragment then 2 MFMAs.
            #pragma unroll
            for (int ks = 0; ks < 4; ++ks) {
                // 8 exp'd regs of this slice: ks<2 -> s0, else s1; base (ks&1)*8
                float e0, e1, e2, e3, e4, e5, e6, e7;
                if (ks == 0)      { e0=s0[0]; e1=s0[1]; e2=s0[2];  e3=s0[3];
                                    e4=s0[4]; e5=s0[5]; e6=s0[6];  e7=s0[7]; }
                else if (ks == 1) { e0=s0[8]; e1=s0[9]; e2=s0[10]; e3=s0[11];
                                    e4=s0[12];e5=s0[13];e6=s0[14]; e7=s0[15]; }
                else if (ks == 2) { e0=s1[0]; e1=s1[1]; e2=s1[2];  e3=s1[3];
                                    e4=s1[4]; e5=s1[5]; e6=s1[6];  e7=s1[7]; }
                else              { e0=s1[8]; e1=s1[9]; e2=s1[10]; e3=s1[11];
                                    e4=s1[12];e5=s1[13];e6=s1[14]; e7=s1[15]; }
                u32 lo01 = pack2(e0, e1), lo23 = pack2(e2, e3);
                u32 hi45 = pack2(e4, e5), hi67 = pack2(e6, e7);
                // exchange the half the partner needs
                u32 send0 = hi ? lo01 : hi45;
                u32 send1 = hi ? lo23 : hi67;
                u32 recv0 = __shfl_xor(send0, 32);
                u32 recv1 = __shfl_xor(send1, 32);
                union { u32 uw[4]; bf16x8 v8; } pu;
                pu.uw[0] = hi ? recv0 : lo01;   // keys base+ (hi? 8,9 : 0,1)
                pu.uw[1] = hi ? recv1 : lo23;
                pu.uw[2] = hi ? hi45 : recv0;   // keys base+ (hi? 12,13 : 4,5)
                pu.uw[3] = hi ? hi67 : recv1;

                int sw = ((ks * 2 + hi) ^ (l31 & 7)) * 8;
                bf16x8 bv0 = *(const bf16x8*)&v_lds[cur][l31 * 64 + sw];
                bf16x8 bv1 = *(const bf16x8*)&v_lds[cur][(32 + l31) * 64 + sw];
                acc0 = __builtin_amdgcn_mfma_f32_32x32x16_bf16(pu.v8, bv0, acc0, 0, 0, 0);
                acc1 = __builtin_amdgcn_mfma_f32_32x32x16_bf16(pu.v8, bv1, acc1, 0, 0, 0);
            }
        }

        __syncthreads();   // drains this iter's async stage; protects buf reuse
        cur ^= 1;
    }

    // final: redistribute l_i (query-indexed) to acc rows, divide, store
    l_scr[w][l31] = l_i;
    asm volatile("s_waitcnt lgkmcnt(0)" ::: "memory");
    #pragma unroll
    for (int reg = 0; reg < 16; ++reg) {
        int row = (reg & 3) + 8 * (reg >> 2) + 4 * hi;
        float inv = 1.f / l_scr[w][row];
        int grow = qt * 128 + w * 32 + row;
        size_t base = (size_t)(b * L_ + grow) * D_ + h * DH_ + l31;
        Ow[base]      = (bf16_t)(acc0[reg] * inv);
        Ow[base + 32] = (bf16_t)(acc1[reg] * inv);
    }
}

extern "C" void kernel_launch(void* const* d_in, const int* in_sizes, int n_in,
                              void* d_out, int out_size, void* d_ws, size_t ws_size,
                              hipStream_t stream)
{
    // Inputs fp32, output fp32. Compute in bf16 MFMA, final store fp32.
    const float* queries = (const float*)d_in[0];
    const float* keys    = (const float*)d_in[1];
    const float* values  = (const float*)d_in[2];
    const float* Wq = (const float*)d_in[3];
    const float* Wk = (const float*)d_in[4];
    const float* Wv = (const float*)d_in[5];
    const float* Wo = (const float*)d_in[6];
    float* out = (float*)d_out;

    const size_t SZ = (size_t)B_ * L_ * D_;   // 8,388,608
    const size_t WZ = (size_t)D_ * D_;        // 1,048,576
    bf16_t* cbuf  = (bf16_t*)d_ws;            // queries bf16 (later attn out)
    bf16_t* cWq   = cbuf + SZ;
    bf16_t* cWk   = cWq + WZ;
    bf16_t* cWv   = cWk + WZ;
    bf16_t* cWo   = cWv + WZ;
    bf16_t* q_ws  = cWo + WZ;
    bf16_t* k_ws  = q_ws + SZ;
    bf16_t* vt_ws = k_ws + SZ;                // [B,H,DH,S]
    bf16_t* a_ws  = cbuf;                     // attn out aliases cbuf (dead)

    // keys/values bf16 scratch carved from d_out (dead until final GEMM).
    bf16_t* ck = (bf16_t*)d_out;
    bf16_t* cv = ck + SZ;

    dim3 gg(D_ / 128, (B_ * L_) / 128);       // (8, 64)

    cvt4_f32_bf16<<<4096, 256, 0, stream>>>(Wq, Wk, Wv, Wo, cWq, cWk, cWv, cWo);
    cvt3_f32_bf16<<<24576, 256, 0, stream>>>(queries, keys, values, cbuf, ck, cv);

    gemm_qkv<<<dim3(D_ / 128, (B_ * L_) / 128, 3), 256, 0, stream>>>(
        cbuf, cWq, q_ws,
        ck,   cWk, k_ws,
        cv,   cWv, vt_ws,
        D_, D_);

    attn_fwd<<<dim3(L_ / 128, H_, B_), 256, 0, stream>>>(q_ws, k_ws, vt_ws, a_ws);

    gemm_bt<<<gg, 256, 0, stream>>>(a_ws, cWo, nullptr, out, B_ * L_, D_, D_, 2);
}

// Round 5
// 381.056 us; speedup vs baseline: 1.5494x; 1.1087x over previous
//
#include <hip/hip_runtime.h>
#include <hip/hip_bf16.h>
#include <stdint.h>

typedef __bf16 bf16_t;
typedef __bf16 bf16x4 __attribute__((ext_vector_type(4)));
typedef __bf16 bf16x8 __attribute__((ext_vector_type(8)));
typedef float  f32x4  __attribute__((ext_vector_type(4)));
typedef float  f32x16 __attribute__((ext_vector_type(16)));
typedef unsigned int u32;

#define B_  4
#define L_  2048
#define D_  1024
#define H_  16
#define DH_ 64

// async global->LDS, 16B per lane. lds ptr is wave-uniform; HW adds lane*16.
__device__ __forceinline__ void async_load16(const bf16_t* g, bf16_t* lds) {
    __builtin_amdgcn_global_load_lds(
        (__attribute__((address_space(1))) void*)g,
        (__attribute__((address_space(3))) void*)lds, 16, 0, 0);
}

// four 1M-element weights in one launch; 262144 float4-chunks per tensor
__global__ __launch_bounds__(256) void cvt4_f32_bf16(
    const float* __restrict__ w0, const float* __restrict__ w1,
    const float* __restrict__ w2, const float* __restrict__ w3,
    bf16_t* __restrict__ o0, bf16_t* __restrict__ o1,
    bf16_t* __restrict__ o2, bf16_t* __restrict__ o3)
{
    int i = blockIdx.x * 256 + threadIdx.x;          // 0 .. 4*262144-1
    int which = i >> 18;
    int j = (i & 262143) * 4;
    const float* w = which == 0 ? w0 : which == 1 ? w1 : which == 2 ? w2 : w3;
    bf16_t*      o = which == 0 ? o0 : which == 1 ? o1 : which == 2 ? o2 : o3;
    f32x4 v = *(const f32x4*)(w + j);
    bf16x4 ov;
    ov[0] = (bf16_t)v[0]; ov[1] = (bf16_t)v[1];
    ov[2] = (bf16_t)v[2]; ov[3] = (bf16_t)v[3];
    *(bf16x4*)(o + j) = ov;
}

// three 8M-element activations (queries/keys/values) in one launch.
__global__ __launch_bounds__(256) void cvt3_f32_bf16(
    const float* __restrict__ a0, const float* __restrict__ a1,
    const float* __restrict__ a2,
    bf16_t* __restrict__ o0, bf16_t* __restrict__ o1, bf16_t* __restrict__ o2)
{
    int i = blockIdx.x * 256 + threadIdx.x;          // 0 .. 3*2^21-1
    int which = i >> 21;
    size_t j = (size_t)(i & ((1 << 21) - 1)) * 4;
    const float* a = which == 0 ? a0 : which == 1 ? a1 : a2;
    bf16_t*      o = which == 0 ? o0 : which == 1 ? o1 : o2;
    f32x4 v = *(const f32x4*)(a + j);
    bf16x4 ov;
    ov[0] = (bf16_t)v[0]; ov[1] = (bf16_t)v[1];
    ov[2] = (bf16_t)v[2]; ov[3] = (bf16_t)v[3];
    *(bf16x4*)(o + j) = ov;
}

// C[M,N] = A[M,K] * B[N,K]^T, bf16 in, fp32 accum. 128x128 tile, 4 waves
// (2x2 of 64x64), 16x16x32 bf16 MFMA.
__device__ __forceinline__ void gemm_bt_body(
    const bf16_t* __restrict__ A, const bf16_t* __restrict__ Bm,
    bf16_t* __restrict__ Cb, float* __restrict__ Cf,
    int N, int K, int mode, bf16_t* lds)
{
    const int t = threadIdx.x;
    const int w = t >> 6, l = t & 63;
    const int quad = l >> 4, l15 = l & 15;
    const int wm = w >> 1, wn = w & 1;
    const int rowBase = blockIdx.y * 128;
    const int colBase = blockIdx.x * 128;

    f32x4 acc[4][4] = {};

    for (int k0 = 0; k0 < K; k0 += 32) {
        #pragma unroll
        for (int q2 = 0; q2 < 2; ++q2) {
            int c = q2 * 256 + w * 64 + l;       // 16B chunk id, 0..511
            int r = c >> 2, kc = c & 3;          // row (64B = 4 chunks/row)
            async_load16(&A[(size_t)(rowBase + r) * K + k0 + kc * 8],
                         &lds[(q2 * 256 + w * 64) * 8]);
            async_load16(&Bm[(size_t)(colBase + r) * K + k0 + kc * 8],
                         &lds[4096 + (q2 * 256 + w * 64) * 8]);
        }
        __syncthreads();

        bf16x8 af[4], bfr[4];
        #pragma unroll
        for (int i = 0; i < 4; ++i) {
            af[i]  = *(const bf16x8*)&lds[(wm * 64 + i * 16 + l15) * 32 + quad * 8];
            bfr[i] = *(const bf16x8*)&lds[4096 + (wn * 64 + i * 16 + l15) * 32 + quad * 8];
        }
        #pragma unroll
        for (int mt = 0; mt < 4; ++mt)
            #pragma unroll
            for (int nt = 0; nt < 4; ++nt)
                acc[mt][nt] = __builtin_amdgcn_mfma_f32_16x16x32_bf16(
                    af[mt], bfr[nt], acc[mt][nt], 0, 0, 0);
        __syncthreads();
    }

    #pragma unroll
    for (int mt = 0; mt < 4; ++mt)
        #pragma unroll
        for (int nt = 0; nt < 4; ++nt)
            #pragma unroll
            for (int r = 0; r < 4; ++r) {
                int row = rowBase + wm * 64 + mt * 16 + quad * 4 + r;  // C/D: row=quad*4+reg
                int col = colBase + wn * 64 + nt * 16 + l15;           //      col=lane&15
                float v = acc[mt][nt][r];
                if (mode == 0) {
                    Cb[(size_t)row * N + col] = (bf16_t)v;
                } else if (mode == 1) {
                    int b = row >> 11, s = row & 2047;   // row = b*2048 + s
                    int h = col >> 6,  d = col & 63;     // col = h*64 + d
                    Cb[(((size_t)((b * H_ + h) * DH_ + d)) << 11) + s] = (bf16_t)v;
                } else {
                    Cf[(size_t)row * N + col] = v;
                }
            }
}

__global__ __launch_bounds__(256) void gemm_bt(
    const bf16_t* __restrict__ A, const bf16_t* __restrict__ Bm,
    bf16_t* __restrict__ Cb, float* __restrict__ Cf,
    int M, int N, int K, int mode)
{
    __shared__ __align__(16) bf16_t lds[8192];
    (void)M;
    gemm_bt_body(A, Bm, Cb, Cf, N, K, mode, lds);
}

// QKV projections fused into one launch (grid.z selects); 1536 blocks
__global__ __launch_bounds__(256) void gemm_qkv(
    const bf16_t* __restrict__ A0, const bf16_t* __restrict__ B0, bf16_t* __restrict__ C0,
    const bf16_t* __restrict__ A1, const bf16_t* __restrict__ B1, bf16_t* __restrict__ C1,
    const bf16_t* __restrict__ A2, const bf16_t* __restrict__ B2, bf16_t* __restrict__ C2,
    int N, int K)
{
    __shared__ __align__(16) bf16_t lds[8192];
    const int z = blockIdx.z;
    const bf16_t* A  = z == 0 ? A0 : z == 1 ? A1 : A2;
    const bf16_t* Bm = z == 0 ? B0 : z == 1 ? B1 : B2;
    bf16_t*       C  = z == 0 ? C0 : z == 1 ? C1 : C2;
    gemm_bt_body(A, Bm, C, nullptr, N, K, z == 2 ? 1 : 0, lds);
}

// ---------------------------------------------------------------------------
// Flash attention, causal — swapped-QK^T 32x32x16 structure, qt-PAIRED for
// load balance.
//
// Causal work per 128-row Q-tile qt is nkt = 2*qt+2 K-tiles. A grid with one
// block per qt has 2..32-unit blocks -> straggler-bound makespan (R4 measured
// 11% occupancy). Pairing qt=p with qt=15-p makes every block exactly 34
// units: grid (8,16,4) = 512 identical blocks = exactly 2/CU, no tail.
// Implementation: outer 2-pass loop over {15-p, p}, full state re-init per
// pass; pass-0's final __syncthreads fences LDS reuse before pass-1 restages.
//
// Softmax in log2 units (exp2 fold): Q pre-scaled by 0.125*log2e, so
// p = exp2(s - m) — drops 32 v_mul per tile-unit per wave. defer-max (T13)
// threshold 8 -> P <= 2^8, f32-safe.
//
// One block = (b, h, 128 Q rows); 4 waves, wave owns 32 rows. KVBLK=64.
// QK^T computes mfma(A=K, B=Q): C col=lane&31 = QUERY q, row = key. Lane
// (l31, hi) holds, for query q=l31, the 32 keys {(reg&3)+8*(reg>>2)+4*hi}
// of each 32-key block; partner lane l^32 holds the complementary 32.
// Softmax fully in-register: 31-op local max/sum tree + ONE __shfl_xor(.,32)
// combine. No p_lds round trip.
//
// P -> PV A-fragments: pa[ks][j] must equal P[q][ks*16 + hi*8 + j].
//   hi=0: words = [own r0r1, own r2r3, partner r0r1, partner r2r3]
//   hi=1: words = [partner r4r5, partner r6r7, own r4r5, own r6r7]
// Exchange via 2 __shfl_xor(.,32) of the half the partner needs + hi-selects.
//
// Layout facts (guide-verified m74/m101) for 32x32x16_bf16:
//   A: row=lane&31, k=(lane>>5)*8+j ; B: col=lane&31, k=(lane>>5)*8+j
//   C: col=lane&31, row=(reg&3)+8*(reg>>2)+4*(lane>>5)
//
// K/V LDS tiles 64x64 bf16, XOR-swizzled (chunk kc of row r at kc^(r&7),
// applied on the GLOBAL source; global_load_lds writes linearly).
// ---------------------------------------------------------------------------
__device__ __forceinline__ u32 pack2(float a, float b) {
    union { u32 u; bf16_t h[2]; } p;
    p.h[0] = (bf16_t)a; p.h[1] = (bf16_t)b;
    return p.u;
}

__device__ __forceinline__ void stage_kv(
    const bf16_t* __restrict__ Kw, const bf16_t* __restrict__ Vt,
    bf16_t* kl, bf16_t* vl, int b, int h, int j0, int w, int l)
{
    #pragma unroll
    for (int q2 = 0; q2 < 2; ++q2) {
        int c  = q2 * 256 + w * 64 + l;      // 16B chunk id, 0..511
        int rr = c >> 3, kc = c & 7;         // row (128B = 8 chunks/row)
        int kcs = kc ^ (rr & 7);             // pre-swizzled global source chunk
        async_load16(&Kw[(size_t)(b * L_ + j0 + rr) * D_ + h * DH_ + kcs * 8],
                     &kl[(q2 * 256 + w * 64) * 8]);
        async_load16(&Vt[((size_t)((b * H_ + h) * DH_ + rr)) * (size_t)L_ + j0 + kcs * 8],
                     &vl[(q2 * 256 + w * 64) * 8]);
    }
}

__global__ __launch_bounds__(256) void attn_fwd(
    const bf16_t* __restrict__ Qw, const bf16_t* __restrict__ Kw,
    const bf16_t* __restrict__ Vt, bf16_t* __restrict__ Ow)
{
    __shared__ __align__(16) bf16_t k_lds[2][4096];  // 2 x 64(s) x 64(d), swz
    __shared__ __align__(16) bf16_t v_lds[2][4096];  // 2 x 64(d) x 64(s), swz
    __shared__ float l_scr[4][32];                   // per-wave redistribute

    const int t = threadIdx.x;
    const int w = t >> 6, l = t & 63;
    const int l31 = l & 31, hi = l >> 5;
    const int pr = blockIdx.x;                    // pair index 0..7
    const int h = blockIdx.y, b = blockIdx.z;

    #pragma unroll 1
    for (int pass = 0; pass < 2; ++pass) {
        const int qt = pass == 0 ? (15 - pr) : pr;    // heavy tile first
        const int qrow = qt * 128 + w * 32 + l31;     // this lane's query

        // Q fragments (B-operand), pre-scaled by 0.125*log2e (exp2 fold)
        bf16x8 bq[4];
        {
            const bf16_t* qp = Qw + (size_t)(b * L_ + qrow) * D_ + h * DH_ + hi * 8;
            #pragma unroll
            for (int kd = 0; kd < 4; ++kd) {
                bq[kd] = *(const bf16x8*)(qp + kd * 16);
                #pragma unroll
                for (int j = 0; j < 8; ++j)
                    bq[kd][j] = (bf16_t)((float)bq[kd][j] * 0.180336880f);
            }
        }

        f32x16 acc0 = {}, acc1 = {};   // O: col=lane&31=d (acc1: d+32), row=q
        float m_i = -1e30f, l_i = 0.f;

        stage_kv(Kw, Vt, k_lds[0], v_lds[0], b, h, 0, w, l);
        __syncthreads();

        const int nkt  = 2 * qt + 2;
        const int wmax = qt * 128 + w * 32 + 31;
        int cur = 0;
        for (int jt = 0; jt < nkt; ++jt) {
            if (jt + 1 < nkt)
                stage_kv(Kw, Vt, k_lds[cur ^ 1], v_lds[cur ^ 1], b, h, (jt + 1) * 64, w, l);

            const int j0 = jt * 64;
            if (j0 <= wmax) {             // wave-uniform: skip fully-masked tile
                // S^T = K * Q^T : s0 = keys 0..31, s1 = keys 32..63 (local)
                f32x16 s0 = {}, s1 = {};
                #pragma unroll
                for (int kd = 0; kd < 4; ++kd) {
                    int sw = ((kd * 2 + hi) ^ (l31 & 7)) * 8;   // same both rows
                    bf16x8 ak0 = *(const bf16x8*)&k_lds[cur][l31 * 64 + sw];
                    bf16x8 ak1 = *(const bf16x8*)&k_lds[cur][(32 + l31) * 64 + sw];
                    s0 = __builtin_amdgcn_mfma_f32_32x32x16_bf16(ak0, bq[kd], s0, 0, 0, 0);
                    s1 = __builtin_amdgcn_mfma_f32_32x32x16_bf16(ak1, bq[kd], s1, 0, 0, 0);
                }

                // causal mask — only the last two K-tiles straddle the diagonal
                if (jt >= 2 * qt) {
                    #pragma unroll
                    for (int reg = 0; reg < 16; ++reg) {
                        int row = (reg & 3) + 8 * (reg >> 2) + 4 * hi;  // local key
                        if (j0 + row > qrow)      s0[reg] = -1e30f;
                        if (j0 + 32 + row > qrow) s1[reg] = -1e30f;
                    }
                }

                // row max: local tree over 32 values + one cross-half combine
                float mt_[16];
                #pragma unroll
                for (int r = 0; r < 16; ++r) mt_[r] = fmaxf(s0[r], s1[r]);
                #pragma unroll
                for (int st = 8; st > 0; st >>= 1)
                    #pragma unroll
                    for (int r = 0; r < st; ++r) mt_[r] = fmaxf(mt_[r], mt_[r + st]);
                float mx = fmaxf(mt_[0], __shfl_xor(mt_[0], 32));

                // defer-max (T13): rescale only when the max actually grew
                int grew = !(mx <= m_i + 8.f);
                if (__any(grew)) {
                    float mn = fmaxf(m_i, mx);
                    float alpha = exp2f(m_i - mn);
                    m_i = mn; l_i *= alpha;
                    l_scr[w][l31] = alpha;     // both hi-halves write same value
                    asm volatile("s_waitcnt lgkmcnt(0)" ::: "memory");
                    #pragma unroll
                    for (int reg = 0; reg < 16; ++reg) {
                        int row = (reg & 3) + 8 * (reg >> 2) + 4 * hi;
                        float a2 = l_scr[w][row];          // broadcast read
                        acc0[reg] *= a2; acc1[reg] *= a2;
                    }
                }

                // p = exp2(s - m) in place; row sum tree + cross-half combine
                #pragma unroll
                for (int r = 0; r < 16; ++r) s0[r] = exp2f(s0[r] - m_i);
                #pragma unroll
                for (int r = 0; r < 16; ++r) s1[r] = exp2f(s1[r] - m_i);
                float st_[16];
                #pragma unroll
                for (int r = 0; r < 16; ++r) st_[r] = s0[r] + s1[r];
                #pragma unroll
                for (int st = 8; st > 0; st >>= 1)
                    #pragma unroll
                    for (int r = 0; r < st; ++r) st_[r] += st_[r + st];
                l_i += st_[0] + __shfl_xor(st_[0], 32);

                // PV: per ks (16-key slice), build A-fragment then 2 MFMAs.
                #pragma unroll
                for (int ks = 0; ks < 4; ++ks) {
                    float e0, e1, e2, e3, e4, e5, e6, e7;
                    if (ks == 0)      { e0=s0[0]; e1=s0[1]; e2=s0[2];  e3=s0[3];
                                        e4=s0[4]; e5=s0[5]; e6=s0[6];  e7=s0[7]; }
                    else if (ks == 1) { e0=s0[8]; e1=s0[9]; e2=s0[10]; e3=s0[11];
                                        e4=s0[12];e5=s0[13];e6=s0[14]; e7=s0[15]; }
                    else if (ks == 2) { e0=s1[0]; e1=s1[1]; e2=s1[2];  e3=s1[3];
                                        e4=s1[4]; e5=s1[5]; e6=s1[6];  e7=s1[7]; }
                    else              { e0=s1[8]; e1=s1[9]; e2=s1[10]; e3=s1[11];
                                        e4=s1[12];e5=s1[13];e6=s1[14]; e7=s1[15]; }
                    u32 lo01 = pack2(e0, e1), lo23 = pack2(e2, e3);
                    u32 hi45 = pack2(e4, e5), hi67 = pack2(e6, e7);
                    // exchange the half the partner needs
                    u32 send0 = hi ? lo01 : hi45;
                    u32 send1 = hi ? lo23 : hi67;
                    u32 recv0 = __shfl_xor(send0, 32);
                    u32 recv1 = __shfl_xor(send1, 32);
                    union { u32 uw[4]; bf16x8 v8; } pu;
                    pu.uw[0] = hi ? recv0 : lo01;   // keys base+ (hi? 8,9 : 0,1)
                    pu.uw[1] = hi ? recv1 : lo23;
                    pu.uw[2] = hi ? hi45 : recv0;   // keys base+ (hi? 12,13:4,5)
                    pu.uw[3] = hi ? hi67 : recv1;

                    int sw = ((ks * 2 + hi) ^ (l31 & 7)) * 8;
                    bf16x8 bv0 = *(const bf16x8*)&v_lds[cur][l31 * 64 + sw];
                    bf16x8 bv1 = *(const bf16x8*)&v_lds[cur][(32 + l31) * 64 + sw];
                    acc0 = __builtin_amdgcn_mfma_f32_32x32x16_bf16(pu.v8, bv0, acc0, 0, 0, 0);
                    acc1 = __builtin_amdgcn_mfma_f32_32x32x16_bf16(pu.v8, bv1, acc1, 0, 0, 0);
                }
            }

            __syncthreads();   // drains this iter's async stage; buf reuse
            cur ^= 1;
        }

        // final: redistribute l_i (query-indexed) to acc rows, divide, store
        l_scr[w][l31] = l_i;
        asm volatile("s_waitcnt lgkmcnt(0)" ::: "memory");
        #pragma unroll
        for (int reg = 0; reg < 16; ++reg) {
            int row = (reg & 3) + 8 * (reg >> 2) + 4 * hi;
            float inv = 1.f / l_scr[w][row];
            int grow = qt * 128 + w * 32 + row;
            size_t base = (size_t)(b * L_ + grow) * D_ + h * DH_ + l31;
            Ow[base]      = (bf16_t)(acc0[reg] * inv);
            Ow[base + 32] = (bf16_t)(acc1[reg] * inv);
        }
        // pass-1 staging is safe: every wave passed the loop's final
        // __syncthreads after its last LDS read; stores above are global-only.
    }
}

extern "C" void kernel_launch(void* const* d_in, const int* in_sizes, int n_in,
                              void* d_out, int out_size, void* d_ws, size_t ws_size,
                              hipStream_t stream)
{
    // Inputs fp32, output fp32. Compute in bf16 MFMA, final store fp32.
    const float* queries = (const float*)d_in[0];
    const float* keys    = (const float*)d_in[1];
    const float* values  = (const float*)d_in[2];
    const float* Wq = (const float*)d_in[3];
    const float* Wk = (const float*)d_in[4];
    const float* Wv = (const float*)d_in[5];
    const float* Wo = (const float*)d_in[6];
    float* out = (float*)d_out;

    const size_t SZ = (size_t)B_ * L_ * D_;   // 8,388,608
    const size_t WZ = (size_t)D_ * D_;        // 1,048,576
    bf16_t* cbuf  = (bf16_t*)d_ws;            // queries bf16 (later attn out)
    bf16_t* cWq   = cbuf + SZ;
    bf16_t* cWk   = cWq + WZ;
    bf16_t* cWv   = cWk + WZ;
    bf16_t* cWo   = cWv + WZ;
    bf16_t* q_ws  = cWo + WZ;
    bf16_t* k_ws  = q_ws + SZ;
    bf16_t* vt_ws = k_ws + SZ;                // [B,H,DH,S]
    bf16_t* a_ws  = cbuf;                     // attn out aliases cbuf (dead)

    // keys/values bf16 scratch carved from d_out (dead until final GEMM).
    bf16_t* ck = (bf16_t*)d_out;
    bf16_t* cv = ck + SZ;

    dim3 gg(D_ / 128, (B_ * L_) / 128);       // (8, 64)

    cvt4_f32_bf16<<<4096, 256, 0, stream>>>(Wq, Wk, Wv, Wo, cWq, cWk, cWv, cWo);
    cvt3_f32_bf16<<<24576, 256, 0, stream>>>(queries, keys, values, cbuf, ck, cv);

    gemm_qkv<<<dim3(D_ / 128, (B_ * L_) / 128, 3), 256, 0, stream>>>(
        cbuf, cWq, q_ws,
        ck,   cWk, k_ws,
        cv,   cWv, vt_ws,
        D_, D_);

    attn_fwd<<<dim3(8, H_, B_), 256, 0, stream>>>(q_ws, k_ws, vt_ws, a_ws);

    gemm_bt<<<gg, 256, 0, stream>>>(a_ws, cWo, nullptr, out, B_ * L_, D_, D_, 2);
}

// Round 6
// 366.187 us; speedup vs baseline: 1.6124x; 1.0406x over previous
//
#include <hip/hip_runtime.h>
#include <hip/hip_bf16.h>
#include <stdint.h>

typedef __bf16 bf16_t;
typedef __bf16 bf16x4 __attribute__((ext_vector_type(4)));
typedef __bf16 bf16x8 __attribute__((ext_vector_type(8)));
typedef float  f32x4  __attribute__((ext_vector_type(4)));
typedef float  f32x16 __attribute__((ext_vector_type(16)));
typedef unsigned int u32;

#define B_  4
#define L_  2048
#define D_  1024
#define H_  16
#define DH_ 64

// async global->LDS, 16B per lane. lds ptr is wave-uniform; HW adds lane*16.
__device__ __forceinline__ void async_load16(const bf16_t* g, bf16_t* lds) {
    __builtin_amdgcn_global_load_lds(
        (__attribute__((address_space(1))) void*)g,
        (__attribute__((address_space(3))) void*)lds, 16, 0, 0);
}

// All fp32->bf16 conversions in ONE launch: 3 activations (2^21 float4 each)
// then 4 weights (2^18 float4 each). 7,340,032 float4s = 28672 blocks.
__global__ __launch_bounds__(256) void cvt_all(
    const float* __restrict__ a0, const float* __restrict__ a1,
    const float* __restrict__ a2,
    const float* __restrict__ w0, const float* __restrict__ w1,
    const float* __restrict__ w2, const float* __restrict__ w3,
    bf16_t* __restrict__ oa0, bf16_t* __restrict__ oa1, bf16_t* __restrict__ oa2,
    bf16_t* __restrict__ ow0, bf16_t* __restrict__ ow1,
    bf16_t* __restrict__ ow2, bf16_t* __restrict__ ow3)
{
    int i = blockIdx.x * 256 + threadIdx.x;
    const float* src; bf16_t* dst; size_t j;
    if (i < 3 * (1 << 21)) {
        int which = i >> 21;
        src = which == 0 ? a0 : which == 1 ? a1 : a2;
        dst = which == 0 ? oa0 : which == 1 ? oa1 : oa2;
        j = (size_t)(i & ((1 << 21) - 1)) * 4;
    } else {
        int k = i - 3 * (1 << 21);
        int which = k >> 18;
        src = which == 0 ? w0 : which == 1 ? w1 : which == 2 ? w2 : w3;
        dst = which == 0 ? ow0 : which == 1 ? ow1 : which == 2 ? ow2 : ow3;
        j = (size_t)(k & ((1 << 18) - 1)) * 4;
    }
    f32x4 v = *(const f32x4*)(src + j);
    bf16x4 ov;
    ov[0] = (bf16_t)v[0]; ov[1] = (bf16_t)v[1];
    ov[2] = (bf16_t)v[2]; ov[3] = (bf16_t)v[3];
    *(bf16x4*)(dst + j) = ov;
}

// ---------------------------------------------------------------------------
// C[M,1024] = A[M,1024] * B[1024,1024]^T, bf16 in, fp32 accum.
// 128x128 tile, 4 waves (2x2 of 64x64), 32x32x16 bf16 MFMA, BK=64.
//
// vs the previous BK=32/16x16x32 body: half the barrier-pairs (16 vs 32 per
// block), 2x FLOP per ds_read_b128 and per barrier, faster MFMA shape
// (2495 vs 2176 TF ubench), and the K/V-proven XOR-swizzled staging (rows of
// 8 x 16B chunks, chunk^=(row&7) pre-applied on the GLOBAL source since
// global_load_lds writes linearly; read with the same XOR) -> measured-zero
// bank conflicts in the attn kernel with this exact geometry.
//
// Layout facts (guide m74/m101, validated by attn R4+): 32x32x16_bf16:
//   A: row=lane&31, k=(lane>>5)*8+j ; B: col=lane&31, k=(lane>>5)*8+j
//   C: col=lane&31, row=(reg&3)+8*(reg>>2)+4*(lane>>5)
//
// mode 0: bf16 row-major out. mode 1: bf16 scatter as Vt[B][H][DH][S].
// mode 2: fp32 row-major out (final projection).
// ---------------------------------------------------------------------------
__device__ __forceinline__ void stage_ab(
    const bf16_t* __restrict__ A, const bf16_t* __restrict__ Bm,
    bf16_t* lds, int rowBase, int colBase, int k0, int t)
{
    const int wbase = t & ~63;             // wave-uniform LDS base component
    #pragma unroll
    for (int sweep = 0; sweep < 4; ++sweep) {
        int c = sweep * 256 + t;           // 16B chunk id, 0..1023
        int r = c >> 3, kc = c & 7;        // row (128B = 8 chunks/row)
        int kcs = kc ^ (r & 7);            // pre-swizzled global source chunk
        async_load16(&A[((size_t)(rowBase + r) << 10) + k0 + kcs * 8],
                     &lds[(sweep * 256 + wbase) * 8]);
        async_load16(&Bm[((size_t)(colBase + r) << 10) + k0 + kcs * 8],
                     &lds[8192 + (sweep * 256 + wbase) * 8]);
    }
}

__device__ __forceinline__ void gemm_bt_body(
    const bf16_t* __restrict__ A, const bf16_t* __restrict__ Bm,
    bf16_t* __restrict__ Cb, float* __restrict__ Cf,
    int mode, bf16_t* lds)
{
    const int t = threadIdx.x;
    const int w = t >> 6, l = t & 63;
    const int l31 = l & 31, hi = l >> 5;
    const int wm = w >> 1, wn = w & 1;
    const int rowBase = blockIdx.y * 128;
    const int colBase = blockIdx.x * 128;

    f32x16 acc[2][2] = {};   // [mf][nf], 32x32 frags

    for (int k0 = 0; k0 < 1024; k0 += 64) {
        stage_ab(A, Bm, lds, rowBase, colBase, k0, t);
        __syncthreads();     // drains vmcnt -> tile visible

        #pragma unroll
        for (int ks = 0; ks < 4; ++ks) {
            int g = ks * 2 + hi;           // 16B chunk of this k16-step
            bf16x8 af[2], bg[2];
            #pragma unroll
            for (int mf = 0; mf < 2; ++mf) {
                int row = wm * 64 + mf * 32 + l31;
                af[mf] = *(const bf16x8*)&lds[row * 64 + ((g ^ (row & 7)) * 8)];
            }
            #pragma unroll
            for (int nf = 0; nf < 2; ++nf) {
                int row = wn * 64 + nf * 32 + l31;
                bg[nf] = *(const bf16x8*)&lds[8192 + row * 64 + ((g ^ (row & 7)) * 8)];
            }
            #pragma unroll
            for (int mf = 0; mf < 2; ++mf)
                #pragma unroll
                for (int nf = 0; nf < 2; ++nf)
                    acc[mf][nf] = __builtin_amdgcn_mfma_f32_32x32x16_bf16(
                        af[mf], bg[nf], acc[mf][nf], 0, 0, 0);
        }
        __syncthreads();     // all reads done before next-tile overwrite
    }

    #pragma unroll
    for (int mf = 0; mf < 2; ++mf)
        #pragma unroll
        for (int nf = 0; nf < 2; ++nf)
            #pragma unroll
            for (int reg = 0; reg < 16; ++reg) {
                int row = rowBase + wm * 64 + mf * 32
                        + (reg & 3) + 8 * (reg >> 2) + 4 * hi;
                int col = colBase + wn * 64 + nf * 32 + l31;
                float v = acc[mf][nf][reg];
                if (mode == 0) {
                    Cb[((size_t)row << 10) + col] = (bf16_t)v;
                } else if (mode == 1) {
                    int b = row >> 11, s = row & 2047;   // row = b*2048 + s
                    int h = col >> 6,  d = col & 63;     // col = h*64 + d
                    Cb[(((size_t)((b * H_ + h) * DH_ + d)) << 11) + s] = (bf16_t)v;
                } else {
                    Cf[((size_t)row << 10) + col] = v;
                }
            }
}

__global__ __launch_bounds__(256) void gemm_bt(
    const bf16_t* __restrict__ A, const bf16_t* __restrict__ Bm,
    bf16_t* __restrict__ Cb, float* __restrict__ Cf, int mode)
{
    __shared__ __align__(16) bf16_t lds[16384];   // A 16KB | B 16KB
    gemm_bt_body(A, Bm, Cb, Cf, mode, lds);
}

// QKV projections fused into one launch (grid.z selects); 1536 blocks
__global__ __launch_bounds__(256) void gemm_qkv(
    const bf16_t* __restrict__ A0, const bf16_t* __restrict__ B0, bf16_t* __restrict__ C0,
    const bf16_t* __restrict__ A1, const bf16_t* __restrict__ B1, bf16_t* __restrict__ C1,
    const bf16_t* __restrict__ A2, const bf16_t* __restrict__ B2, bf16_t* __restrict__ C2)
{
    __shared__ __align__(16) bf16_t lds[16384];
    const int z = blockIdx.z;
    const bf16_t* A  = z == 0 ? A0 : z == 1 ? A1 : A2;
    const bf16_t* Bm = z == 0 ? B0 : z == 1 ? B1 : B2;
    bf16_t*       C  = z == 0 ? C0 : z == 1 ? C1 : C2;
    gemm_bt_body(A, Bm, C, nullptr, z == 2 ? 1 : 0, lds);
}

// ---------------------------------------------------------------------------
// Flash attention, causal — swapped-QK^T 32x32x16, qt-paired load balance,
// log2-domain softmax, defer-max. UNCHANGED from R5 (verified, 110.6 us).
// ---------------------------------------------------------------------------
__device__ __forceinline__ u32 pack2(float a, float b) {
    union { u32 u; bf16_t h[2]; } p;
    p.h[0] = (bf16_t)a; p.h[1] = (bf16_t)b;
    return p.u;
}

__device__ __forceinline__ void stage_kv(
    const bf16_t* __restrict__ Kw, const bf16_t* __restrict__ Vt,
    bf16_t* kl, bf16_t* vl, int b, int h, int j0, int w, int l)
{
    #pragma unroll
    for (int q2 = 0; q2 < 2; ++q2) {
        int c  = q2 * 256 + w * 64 + l;      // 16B chunk id, 0..511
        int rr = c >> 3, kc = c & 7;         // row (128B = 8 chunks/row)
        int kcs = kc ^ (rr & 7);             // pre-swizzled global source chunk
        async_load16(&Kw[(size_t)(b * L_ + j0 + rr) * D_ + h * DH_ + kcs * 8],
                     &kl[(q2 * 256 + w * 64) * 8]);
        async_load16(&Vt[((size_t)((b * H_ + h) * DH_ + rr)) * (size_t)L_ + j0 + kcs * 8],
                     &vl[(q2 * 256 + w * 64) * 8]);
    }
}

__global__ __launch_bounds__(256) void attn_fwd(
    const bf16_t* __restrict__ Qw, const bf16_t* __restrict__ Kw,
    const bf16_t* __restrict__ Vt, bf16_t* __restrict__ Ow)
{
    __shared__ __align__(16) bf16_t k_lds[2][4096];  // 2 x 64(s) x 64(d), swz
    __shared__ __align__(16) bf16_t v_lds[2][4096];  // 2 x 64(d) x 64(s), swz
    __shared__ float l_scr[4][32];                   // per-wave redistribute

    const int t = threadIdx.x;
    const int w = t >> 6, l = t & 63;
    const int l31 = l & 31, hi = l >> 5;
    const int pr = blockIdx.x;                    // pair index 0..7
    const int h = blockIdx.y, b = blockIdx.z;

    #pragma unroll 1
    for (int pass = 0; pass < 2; ++pass) {
        const int qt = pass == 0 ? (15 - pr) : pr;    // heavy tile first
        const int qrow = qt * 128 + w * 32 + l31;     // this lane's query

        // Q fragments (B-operand), pre-scaled by 0.125*log2e (exp2 fold)
        bf16x8 bq[4];
        {
            const bf16_t* qp = Qw + (size_t)(b * L_ + qrow) * D_ + h * DH_ + hi * 8;
            #pragma unroll
            for (int kd = 0; kd < 4; ++kd) {
                bq[kd] = *(const bf16x8*)(qp + kd * 16);
                #pragma unroll
                for (int j = 0; j < 8; ++j)
                    bq[kd][j] = (bf16_t)((float)bq[kd][j] * 0.180336880f);
            }
        }

        f32x16 acc0 = {}, acc1 = {};   // O: col=lane&31=d (acc1: d+32), row=q
        float m_i = -1e30f, l_i = 0.f;

        stage_kv(Kw, Vt, k_lds[0], v_lds[0], b, h, 0, w, l);
        __syncthreads();

        const int nkt  = 2 * qt + 2;
        const int wmax = qt * 128 + w * 32 + 31;
        int cur = 0;
        for (int jt = 0; jt < nkt; ++jt) {
            if (jt + 1 < nkt)
                stage_kv(Kw, Vt, k_lds[cur ^ 1], v_lds[cur ^ 1], b, h, (jt + 1) * 64, w, l);

            const int j0 = jt * 64;
            if (j0 <= wmax) {             // wave-uniform: skip fully-masked tile
                // S^T = K * Q^T : s0 = keys 0..31, s1 = keys 32..63 (local)
                f32x16 s0 = {}, s1 = {};
                #pragma unroll
                for (int kd = 0; kd < 4; ++kd) {
                    int sw = ((kd * 2 + hi) ^ (l31 & 7)) * 8;   // same both rows
                    bf16x8 ak0 = *(const bf16x8*)&k_lds[cur][l31 * 64 + sw];
                    bf16x8 ak1 = *(const bf16x8*)&k_lds[cur][(32 + l31) * 64 + sw];
                    s0 = __builtin_amdgcn_mfma_f32_32x32x16_bf16(ak0, bq[kd], s0, 0, 0, 0);
                    s1 = __builtin_amdgcn_mfma_f32_32x32x16_bf16(ak1, bq[kd], s1, 0, 0, 0);
                }

                // causal mask — only the last two K-tiles straddle the diagonal
                if (jt >= 2 * qt) {
                    #pragma unroll
                    for (int reg = 0; reg < 16; ++reg) {
                        int row = (reg & 3) + 8 * (reg >> 2) + 4 * hi;  // local key
                        if (j0 + row > qrow)      s0[reg] = -1e30f;
                        if (j0 + 32 + row > qrow) s1[reg] = -1e30f;
                    }
                }

                // row max: local tree over 32 values + one cross-half combine
                float mt_[16];
                #pragma unroll
                for (int r = 0; r < 16; ++r) mt_[r] = fmaxf(s0[r], s1[r]);
                #pragma unroll
                for (int st = 8; st > 0; st >>= 1)
                    #pragma unroll
                    for (int r = 0; r < st; ++r) mt_[r] = fmaxf(mt_[r], mt_[r + st]);
                float mx = fmaxf(mt_[0], __shfl_xor(mt_[0], 32));

                // defer-max (T13): rescale only when the max actually grew
                int grew = !(mx <= m_i + 8.f);
                if (__any(grew)) {
                    float mn = fmaxf(m_i, mx);
                    float alpha = exp2f(m_i - mn);
                    m_i = mn; l_i *= alpha;
                    l_scr[w][l31] = alpha;     // both hi-halves write same value
                    asm volatile("s_waitcnt lgkmcnt(0)" ::: "memory");
                    #pragma unroll
                    for (int reg = 0; reg < 16; ++reg) {
                        int row = (reg & 3) + 8 * (reg >> 2) + 4 * hi;
                        float a2 = l_scr[w][row];          // broadcast read
                        acc0[reg] *= a2; acc1[reg] *= a2;
                    }
                }

                // p = exp2(s - m) in place; row sum tree + cross-half combine
                #pragma unroll
                for (int r = 0; r < 16; ++r) s0[r] = exp2f(s0[r] - m_i);
                #pragma unroll
                for (int r = 0; r < 16; ++r) s1[r] = exp2f(s1[r] - m_i);
                float st_[16];
                #pragma unroll
                for (int r = 0; r < 16; ++r) st_[r] = s0[r] + s1[r];
                #pragma unroll
                for (int st = 8; st > 0; st >>= 1)
                    #pragma unroll
                    for (int r = 0; r < st; ++r) st_[r] += st_[r + st];
                l_i += st_[0] + __shfl_xor(st_[0], 32);

                // PV: per ks (16-key slice), build A-fragment then 2 MFMAs.
                #pragma unroll
                for (int ks = 0; ks < 4; ++ks) {
                    float e0, e1, e2, e3, e4, e5, e6, e7;
                    if (ks == 0)      { e0=s0[0]; e1=s0[1]; e2=s0[2];  e3=s0[3];
                                        e4=s0[4]; e5=s0[5]; e6=s0[6];  e7=s0[7]; }
                    else if (ks == 1) { e0=s0[8]; e1=s0[9]; e2=s0[10]; e3=s0[11];
                                        e4=s0[12];e5=s0[13];e6=s0[14]; e7=s0[15]; }
                    else if (ks == 2) { e0=s1[0]; e1=s1[1]; e2=s1[2];  e3=s1[3];
                                        e4=s1[4]; e5=s1[5]; e6=s1[6];  e7=s1[7]; }
                    else              { e0=s1[8]; e1=s1[9]; e2=s1[10]; e3=s1[11];
                                        e4=s1[12];e5=s1[13];e6=s1[14]; e7=s1[15]; }
                    u32 lo01 = pack2(e0, e1), lo23 = pack2(e2, e3);
                    u32 hi45 = pack2(e4, e5), hi67 = pack2(e6, e7);
                    // exchange the half the partner needs
                    u32 send0 = hi ? lo01 : hi45;
                    u32 send1 = hi ? lo23 : hi67;
                    u32 recv0 = __shfl_xor(send0, 32);
                    u32 recv1 = __shfl_xor(send1, 32);
                    union { u32 uw[4]; bf16x8 v8; } pu;
                    pu.uw[0] = hi ? recv0 : lo01;   // keys base+ (hi? 8,9 : 0,1)
                    pu.uw[1] = hi ? recv1 : lo23;
                    pu.uw[2] = hi ? hi45 : recv0;   // keys base+ (hi? 12,13:4,5)
                    pu.uw[3] = hi ? hi67 : recv1;

                    int sw = ((ks * 2 + hi) ^ (l31 & 7)) * 8;
                    bf16x8 bv0 = *(const bf16x8*)&v_lds[cur][l31 * 64 + sw];
                    bf16x8 bv1 = *(const bf16x8*)&v_lds[cur][(32 + l31) * 64 + sw];
                    acc0 = __builtin_amdgcn_mfma_f32_32x32x16_bf16(pu.v8, bv0, acc0, 0, 0, 0);
                    acc1 = __builtin_amdgcn_mfma_f32_32x32x16_bf16(pu.v8, bv1, acc1, 0, 0, 0);
                }
            }

            __syncthreads();   // drains this iter's async stage; buf reuse
            cur ^= 1;
        }

        // final: redistribute l_i (query-indexed) to acc rows, divide, store
        l_scr[w][l31] = l_i;
        asm volatile("s_waitcnt lgkmcnt(0)" ::: "memory");
        #pragma unroll
        for (int reg = 0; reg < 16; ++reg) {
            int row = (reg & 3) + 8 * (reg >> 2) + 4 * hi;
            float inv = 1.f / l_scr[w][row];
            int grow = qt * 128 + w * 32 + row;
            size_t base = (size_t)(b * L_ + grow) * D_ + h * DH_ + l31;
            Ow[base]      = (bf16_t)(acc0[reg] * inv);
            Ow[base + 32] = (bf16_t)(acc1[reg] * inv);
        }
        // pass-1 staging is safe: every wave passed the loop's final
        // __syncthreads after its last LDS read; stores above are global-only.
    }
}

extern "C" void kernel_launch(void* const* d_in, const int* in_sizes, int n_in,
                              void* d_out, int out_size, void* d_ws, size_t ws_size,
                              hipStream_t stream)
{
    // Inputs fp32, output fp32. Compute in bf16 MFMA, final store fp32.
    const float* queries = (const float*)d_in[0];
    const float* keys    = (const float*)d_in[1];
    const float* values  = (const float*)d_in[2];
    const float* Wq = (const float*)d_in[3];
    const float* Wk = (const float*)d_in[4];
    const float* Wv = (const float*)d_in[5];
    const float* Wo = (const float*)d_in[6];
    float* out = (float*)d_out;

    const size_t SZ = (size_t)B_ * L_ * D_;   // 8,388,608
    const size_t WZ = (size_t)D_ * D_;        // 1,048,576
    bf16_t* cbuf  = (bf16_t*)d_ws;            // queries bf16 (later attn out)
    bf16_t* cWq   = cbuf + SZ;
    bf16_t* cWk   = cWq + WZ;
    bf16_t* cWv   = cWk + WZ;
    bf16_t* cWo   = cWv + WZ;
    bf16_t* q_ws  = cWo + WZ;
    bf16_t* k_ws  = q_ws + SZ;
    bf16_t* vt_ws = k_ws + SZ;                // [B,H,DH,S]
    bf16_t* a_ws  = cbuf;                     // attn out aliases cbuf (dead)

    // keys/values bf16 scratch carved from d_out (dead until final GEMM).
    bf16_t* ck = (bf16_t*)d_out;
    bf16_t* cv = ck + SZ;

    cvt_all<<<28672, 256, 0, stream>>>(queries, keys, values, Wq, Wk, Wv, Wo,
                                       cbuf, ck, cv, cWq, cWk, cWv, cWo);

    gemm_qkv<<<dim3(D_ / 128, (B_ * L_) / 128, 3), 256, 0, stream>>>(
        cbuf, cWq, q_ws,
        ck,   cWk, k_ws,
        cv,   cWv, vt_ws);

    attn_fwd<<<dim3(8, H_, B_), 256, 0, stream>>>(q_ws, k_ws, vt_ws, a_ws);

    gemm_bt<<<dim3(D_ / 128, (B_ * L_) / 128), 256, 0, stream>>>(
        a_ws, cWo, nullptr, out, 2);
}

// Round 8
// 324.156 us; speedup vs baseline: 1.8214x; 1.1297x over previous
//
#include <hip/hip_runtime.h>
#include <hip/hip_bf16.h>
#include <stdint.h>

typedef __bf16 bf16_t;
typedef __bf16 bf16x4 __attribute__((ext_vector_type(4)));
typedef __bf16 bf16x8 __attribute__((ext_vector_type(8)));
typedef float  f32x4  __attribute__((ext_vector_type(4)));
typedef float  f32x16 __attribute__((ext_vector_type(16)));
typedef unsigned int u32;

#define B_  4
#define L_  2048
#define D_  1024
#define H_  16
#define DH_ 64

// async global->LDS, 16B per lane. lds ptr is wave-uniform; HW adds lane*16.
__device__ __forceinline__ void async_load16(const bf16_t* g, bf16_t* lds) {
    __builtin_amdgcn_global_load_lds(
        (__attribute__((address_space(1))) void*)g,
        (__attribute__((address_space(3))) void*)lds, 16, 0, 0);
}

// All fp32->bf16 conversions in ONE launch: 3 activations (2^21 float4 each)
// then 4 weights (2^18 float4 each). 7,340,032 float4s = 28672 blocks.
__global__ __launch_bounds__(256) void cvt_all(
    const float* __restrict__ a0, const float* __restrict__ a1,
    const float* __restrict__ a2,
    const float* __restrict__ w0, const float* __restrict__ w1,
    const float* __restrict__ w2, const float* __restrict__ w3,
    bf16_t* __restrict__ oa0, bf16_t* __restrict__ oa1, bf16_t* __restrict__ oa2,
    bf16_t* __restrict__ ow0, bf16_t* __restrict__ ow1,
    bf16_t* __restrict__ ow2, bf16_t* __restrict__ ow3)
{
    int i = blockIdx.x * 256 + threadIdx.x;
    const float* src; bf16_t* dst; size_t j;
    if (i < 3 * (1 << 21)) {
        int which = i >> 21;
        src = which == 0 ? a0 : which == 1 ? a1 : a2;
        dst = which == 0 ? oa0 : which == 1 ? oa1 : oa2;
        j = (size_t)(i & ((1 << 21) - 1)) * 4;
    } else {
        int k = i - 3 * (1 << 21);
        int which = k >> 18;
        src = which == 0 ? w0 : which == 1 ? w1 : which == 2 ? w2 : w3;
        dst = which == 0 ? ow0 : which == 1 ? ow1 : which == 2 ? ow2 : ow3;
        j = (size_t)(k & ((1 << 18) - 1)) * 4;
    }
    f32x4 v = *(const f32x4*)(src + j);
    bf16x4 ov;
    ov[0] = (bf16_t)v[0]; ov[1] = (bf16_t)v[1];
    ov[2] = (bf16_t)v[2]; ov[3] = (bf16_t)v[3];
    *(bf16x4*)(dst + j) = ov;
}

// ---------------------------------------------------------------------------
// C[M,1024] = A[M,1024] * B[1024,1024]^T, bf16 in, fp32 accum.
// 128x128 tile, 4 waves (2x2 of 64x64), 32x32x16 bf16 MFMA, BK=64.
//
// XCD-chunked swizzle (T1): HW dispatches flat block ids round-robin across
// the 8 XCDs. Remap f -> (f%8)*64 + f/8 so XCD j processes y-rows [8j,8j+8):
// its A working set (8 panels x 256KB = 2MB) becomes L2-resident instead of
// being re-fetched by every block. Grid must be (8,64[,z]); 512 % 8 == 0 so
// each z-slice stays aligned.
//
// Layout facts (guide m74/m101, validated by attn R4+): 32x32x16_bf16:
//   A: row=lane&31, k=(lane>>5)*8+j ; B: col=lane&31, k=(lane>>5)*8+j
//   C: col=lane&31, row=(reg&3)+8*(reg>>2)+4*(lane>>5)
//
// mode 0: bf16 row-major out. mode 2: fp32 row-major out (final projection).
// (The old mode-1 Vt scatter — 2B stores at 4KB stride, ~32x L2 transaction
// amplification — is replaced by a coalesced transpose kernel.)
// ---------------------------------------------------------------------------
__device__ __forceinline__ void stage_ab(
    const bf16_t* __restrict__ A, const bf16_t* __restrict__ Bm,
    bf16_t* lds, int rowBase, int colBase, int k0, int t)
{
    const int wbase = t & ~63;             // wave-uniform LDS base component
    #pragma unroll
    for (int sweep = 0; sweep < 4; ++sweep) {
        int c = sweep * 256 + t;           // 16B chunk id, 0..1023
        int r = c >> 3, kc = c & 7;        // row (128B = 8 chunks/row)
        int kcs = kc ^ (r & 7);            // pre-swizzled global source chunk
        async_load16(&A[((size_t)(rowBase + r) << 10) + k0 + kcs * 8],
                     &lds[(sweep * 256 + wbase) * 8]);
        async_load16(&Bm[((size_t)(colBase + r) << 10) + k0 + kcs * 8],
                     &lds[8192 + (sweep * 256 + wbase) * 8]);
    }
}

__device__ __forceinline__ void gemm_bt_body(
    const bf16_t* __restrict__ A, const bf16_t* __restrict__ Bm,
    bf16_t* __restrict__ Cb, float* __restrict__ Cf,
    int mode, bf16_t* lds)
{
    const int t = threadIdx.x;
    const int w = t >> 6, l = t & 63;
    const int l31 = l & 31, hi = l >> 5;
    const int wm = w >> 1, wn = w & 1;
    // XCD-chunked swizzle: grid is (8, 64); flat id f = bx + by*8.
    const int f  = blockIdx.x + (blockIdx.y << 3);
    const int nf = ((f & 7) << 6) + (f >> 3);
    const int rowBase = (nf >> 3) * 128;
    const int colBase = (nf & 7) * 128;

    f32x16 acc[2][2] = {};   // [mf][nf], 32x32 frags

    for (int k0 = 0; k0 < 1024; k0 += 64) {
        stage_ab(A, Bm, lds, rowBase, colBase, k0, t);
        __syncthreads();     // drains vmcnt -> tile visible

        #pragma unroll
        for (int ks = 0; ks < 4; ++ks) {
            int g = ks * 2 + hi;           // 16B chunk of this k16-step
            bf16x8 af[2], bg[2];
            #pragma unroll
            for (int mf = 0; mf < 2; ++mf) {
                int row = wm * 64 + mf * 32 + l31;
                af[mf] = *(const bf16x8*)&lds[row * 64 + ((g ^ (row & 7)) * 8)];
            }
            #pragma unroll
            for (int nfi = 0; nfi < 2; ++nfi) {
                int row = wn * 64 + nfi * 32 + l31;
                bg[nfi] = *(const bf16x8*)&lds[8192 + row * 64 + ((g ^ (row & 7)) * 8)];
            }
            #pragma unroll
            for (int mf = 0; mf < 2; ++mf)
                #pragma unroll
                for (int nfi = 0; nfi < 2; ++nfi)
                    acc[mf][nfi] = __builtin_amdgcn_mfma_f32_32x32x16_bf16(
                        af[mf], bg[nfi], acc[mf][nfi], 0, 0, 0);
        }
        __syncthreads();     // all reads done before next-tile overwrite
    }

    #pragma unroll
    for (int mf = 0; mf < 2; ++mf)
        #pragma unroll
        for (int nfi = 0; nfi < 2; ++nfi)
            #pragma unroll
            for (int reg = 0; reg < 16; ++reg) {
                int row = rowBase + wm * 64 + mf * 32
                        + (reg & 3) + 8 * (reg >> 2) + 4 * hi;
                int col = colBase + wn * 64 + nfi * 32 + l31;
                float v = acc[mf][nfi][reg];
                if (mode == 0) {
                    Cb[((size_t)row << 10) + col] = (bf16_t)v;
                } else {
                    Cf[((size_t)row << 10) + col] = v;
                }
            }
}

__global__ __launch_bounds__(256) void gemm_bt(
    const bf16_t* __restrict__ A, const bf16_t* __restrict__ Bm,
    bf16_t* __restrict__ Cb, float* __restrict__ Cf, int mode)
{
    __shared__ __align__(16) bf16_t lds[16384];   // A 16KB | B 16KB
    gemm_bt_body(A, Bm, Cb, Cf, mode, lds);
}

// QKV projections fused into one launch (grid.z selects); 1536 blocks.
// All three outputs row-major now (V transposed by transpose_v after).
__global__ __launch_bounds__(256) void gemm_qkv(
    const bf16_t* __restrict__ A0, const bf16_t* __restrict__ B0, bf16_t* __restrict__ C0,
    const bf16_t* __restrict__ A1, const bf16_t* __restrict__ B1, bf16_t* __restrict__ C1,
    const bf16_t* __restrict__ A2, const bf16_t* __restrict__ B2, bf16_t* __restrict__ C2)
{
    __shared__ __align__(16) bf16_t lds[16384];
    const int z = blockIdx.z;
    const bf16_t* A  = z == 0 ? A0 : z == 1 ? A1 : A2;
    const bf16_t* Bm = z == 0 ? B0 : z == 1 ? B1 : B2;
    bf16_t*       C  = z == 0 ? C0 : z == 1 ? C1 : C2;
    gemm_bt_body(A, Bm, C, nullptr, 0, lds);
}

// ---------------------------------------------------------------------------
// V row-major [B*L][1024] -> Vt[B][H][64][2048], via 64x64 LDS tiles.
// Both global read and write fully coalesced (16B/lane). 2048 blocks.
// ---------------------------------------------------------------------------
__global__ __launch_bounds__(256) void transpose_v(
    const bf16_t* __restrict__ Vr, bf16_t* __restrict__ Vt)
{
    __shared__ __align__(16) bf16_t T[64][72];   // T[d][s], padded rows
    const int t = threadIdx.x;
    const int st = blockIdx.x;                   // s-tile 0..31
    const int h = blockIdx.y, b = blockIdx.z;

    #pragma unroll
    for (int k = 0; k < 2; ++k) {
        int c = k * 256 + t;                     // 0..511
        int s = c >> 3, dch = c & 7;             // row s, 16B d-chunk
        bf16x8 v = *(const bf16x8*)
            &Vr[(size_t)(b * L_ + st * 64 + s) * D_ + h * DH_ + dch * 8];
        #pragma unroll
        for (int e = 0; e < 8; ++e)
            T[dch * 8 + e][s] = v[e];
    }
    __syncthreads();
    #pragma unroll
    for (int k = 0; k < 2; ++k) {
        int c = k * 256 + t;
        int d = c >> 3, sch = c & 7;             // row d, 16B s-chunk
        bf16x8 v = *(const bf16x8*)&T[d][sch * 8];
        *(bf16x8*)&Vt[(((size_t)((b * H_ + h) * DH_ + d)) << 11)
                      + st * 64 + sch * 8] = v;
    }
}

// ---------------------------------------------------------------------------
// Flash attention, causal — swapped-QK^T 32x32x16, qt-paired load balance,
// log2-domain softmax, defer-max. K-row permutation kills the PV cross-lane
// exchange.
//
// K staging loads LDS row m from global key sigma(m), sigma = swap bits 2<->3
// (involution). QK^T C-reg key mapping becomes
//     key = (r&7) + 8*hi + 16*(r>>3)   (+32 for s1)
// which IS the PV A-fragment order: pa[ks][j] = s_regs[8*(ks&1)+j] of
// s0 (ks<2) / s1 (ks>=2) — own lane, zero shuffles, zero selects.
// V staging unchanged; sum/max/rescale are key-order-agnostic; the causal
// mask uses the permuted key formula.
// ---------------------------------------------------------------------------
__device__ __forceinline__ u32 pack2(float a, float b) {
    union { u32 u; bf16_t h[2]; } p;
    p.h[0] = (bf16_t)a; p.h[1] = (bf16_t)b;
    return p.u;
}

__device__ __forceinline__ void stage_kv(
    const bf16_t* __restrict__ Kw, const bf16_t* __restrict__ Vt,
    bf16_t* kl, bf16_t* vl, int b, int h, int j0, int w, int l)
{
    #pragma unroll
    for (int q2 = 0; q2 < 2; ++q2) {
        int c  = q2 * 256 + w * 64 + l;      // 16B chunk id, 0..511
        int rr = c >> 3, kc = c & 7;         // row (128B = 8 chunks/row)
        int kcs = kc ^ (rr & 7);             // pre-swizzled global source chunk
        // K: LDS row rr holds key sigma(rr) = rr with bits 2,3 swapped
        int rs = (rr & ~12) | ((rr & 4) << 1) | ((rr & 8) >> 1);
        async_load16(&Kw[(size_t)(b * L_ + j0 + rs) * D_ + h * DH_ + kcs * 8],
                     &kl[(q2 * 256 + w * 64) * 8]);
        async_load16(&Vt[((size_t)((b * H_ + h) * DH_ + rr)) * (size_t)L_ + j0 + kcs * 8],
                     &vl[(q2 * 256 + w * 64) * 8]);
    }
}

__global__ __launch_bounds__(256) void attn_fwd(
    const bf16_t* __restrict__ Qw, const bf16_t* __restrict__ Kw,
    const bf16_t* __restrict__ Vt, bf16_t* __restrict__ Ow)
{
    __shared__ __align__(16) bf16_t k_lds[2][4096];  // 2 x 64(s) x 64(d), swz
    __shared__ __align__(16) bf16_t v_lds[2][4096];  // 2 x 64(d) x 64(s), swz
    __shared__ float l_scr[4][32];                   // per-wave redistribute

    const int t = threadIdx.x;
    const int w = t >> 6, l = t & 63;
    const int l31 = l & 31, hi = l >> 5;
    const int pr = blockIdx.x;                    // pair index 0..7
    const int h = blockIdx.y, b = blockIdx.z;

    #pragma unroll 1
    for (int pass = 0; pass < 2; ++pass) {
        const int qt = pass == 0 ? (15 - pr) : pr;    // heavy tile first
        const int qrow = qt * 128 + w * 32 + l31;     // this lane's query

        // Q fragments (B-operand), pre-scaled by 0.125*log2e (exp2 fold)
        bf16x8 bq[4];
        {
            const bf16_t* qp = Qw + (size_t)(b * L_ + qrow) * D_ + h * DH_ + hi * 8;
            #pragma unroll
            for (int kd = 0; kd < 4; ++kd) {
                bq[kd] = *(const bf16x8*)(qp + kd * 16);
                #pragma unroll
                for (int j = 0; j < 8; ++j)
                    bq[kd][j] = (bf16_t)((float)bq[kd][j] * 0.180336880f);
            }
        }

        f32x16 acc0 = {}, acc1 = {};   // O: reg=query-row, l31=d (acc1: d+32)
        float m_i = -1e30f, l_i = 0.f;

        stage_kv(Kw, Vt, k_lds[0], v_lds[0], b, h, 0, w, l);
        __syncthreads();

        const int nkt  = 2 * qt + 2;
        const int wmax = qt * 128 + w * 32 + 31;
        int cur = 0;
        for (int jt = 0; jt < nkt; ++jt) {
            if (jt + 1 < nkt)
                stage_kv(Kw, Vt, k_lds[cur ^ 1], v_lds[cur ^ 1], b, h, (jt + 1) * 64, w, l);

            const int j0 = jt * 64;
            if (j0 <= wmax) {             // wave-uniform: skip fully-masked tile
                // S^T = K * Q^T : s0 = key-positions 0..31, s1 = 32..63
                f32x16 s0 = {}, s1 = {};
                #pragma unroll
                for (int kd = 0; kd < 4; ++kd) {
                    int sw = ((kd * 2 + hi) ^ (l31 & 7)) * 8;   // same both rows
                    bf16x8 ak0 = *(const bf16x8*)&k_lds[cur][l31 * 64 + sw];
                    bf16x8 ak1 = *(const bf16x8*)&k_lds[cur][(32 + l31) * 64 + sw];
                    s0 = __builtin_amdgcn_mfma_f32_32x32x16_bf16(ak0, bq[kd], s0, 0, 0, 0);
                    s1 = __builtin_amdgcn_mfma_f32_32x32x16_bf16(ak1, bq[kd], s1, 0, 0, 0);
                }

                // causal mask — permuted key = (r&7) + 8*hi + 16*(r>>3)
                if (jt >= 2 * qt) {
                    #pragma unroll
                    for (int reg = 0; reg < 16; ++reg) {
                        int key = (reg & 7) + 8 * hi + 16 * (reg >> 3);
                        if (j0 + key > qrow)      s0[reg] = -1e30f;
                        if (j0 + 32 + key > qrow) s1[reg] = -1e30f;
                    }
                }

                // row max: local tree over 32 values + one cross-half combine
                float mt_[16];
                #pragma unroll
                for (int r = 0; r < 16; ++r) mt_[r] = fmaxf(s0[r], s1[r]);
                #pragma unroll
                for (int st = 8; st > 0; st >>= 1)
                    #pragma unroll
                    for (int r = 0; r < st; ++r) mt_[r] = fmaxf(mt_[r], mt_[r + st]);
                float mx = fmaxf(mt_[0], __shfl_xor(mt_[0], 32));

                // defer-max (T13): rescale only when the max actually grew
                int grew = !(mx <= m_i + 8.f);
                if (__any(grew)) {
                    float mn = fmaxf(m_i, mx);
                    float alpha = exp2f(m_i - mn);
                    m_i = mn; l_i *= alpha;
                    l_scr[w][l31] = alpha;     // both hi-halves write same value
                    asm volatile("s_waitcnt lgkmcnt(0)" ::: "memory");
                    #pragma unroll
                    for (int reg = 0; reg < 16; ++reg) {
                        int row = (reg & 3) + 8 * (reg >> 2) + 4 * hi;
                        float a2 = l_scr[w][row];          // broadcast read
                        acc0[reg] *= a2; acc1[reg] *= a2;
                    }
                }

                // p = exp2(s - m) in place; row sum tree + cross-half combine
                #pragma unroll
                for (int r = 0; r < 16; ++r) s0[r] = exp2f(s0[r] - m_i);
                #pragma unroll
                for (int r = 0; r < 16; ++r) s1[r] = exp2f(s1[r] - m_i);
                float st_[16];
                #pragma unroll
                for (int r = 0; r < 16; ++r) st_[r] = s0[r] + s1[r];
                #pragma unroll
                for (int st = 8; st > 0; st >>= 1)
                    #pragma unroll
                    for (int r = 0; r < st; ++r) st_[r] += st_[r + st];
                l_i += st_[0] + __shfl_xor(st_[0], 32);

                // PV: pa[ks] = own regs 8*(ks&1)..+7 of s0/s1 — no exchange.
                const float* e0p = (const float*)&s0;
                const float* e1p = (const float*)&s1;
                #pragma unroll
                for (int ks = 0; ks < 4; ++ks) {
                    const float* e = (ks < 2) ? e0p : e1p;
                    const int base = (ks & 1) * 8;
                    union { u32 uw[4]; bf16x8 v8; } pu;
                    pu.uw[0] = pack2(e[base + 0], e[base + 1]);
                    pu.uw[1] = pack2(e[base + 2], e[base + 3]);
                    pu.uw[2] = pack2(e[base + 4], e[base + 5]);
                    pu.uw[3] = pack2(e[base + 6], e[base + 7]);

                    int sw = ((ks * 2 + hi) ^ (l31 & 7)) * 8;
                    bf16x8 bv0 = *(const bf16x8*)&v_lds[cur][l31 * 64 + sw];
                    bf16x8 bv1 = *(const bf16x8*)&v_lds[cur][(32 + l31) * 64 + sw];
                    acc0 = __builtin_amdgcn_mfma_f32_32x32x16_bf16(pu.v8, bv0, acc0, 0, 0, 0);
                    acc1 = __builtin_amdgcn_mfma_f32_32x32x16_bf16(pu.v8, bv1, acc1, 0, 0, 0);
                }
            }

            __syncthreads();   // drains this iter's async stage; buf reuse
            cur ^= 1;
        }

        // final: redistribute l_i (query-indexed) to acc rows, divide, store
        l_scr[w][l31] = l_i;
        asm volatile("s_waitcnt lgkmcnt(0)" ::: "memory");
        #pragma unroll
        for (int reg = 0; reg < 16; ++reg) {
            int row = (reg & 3) + 8 * (reg >> 2) + 4 * hi;
            float inv = 1.f / l_scr[w][row];
            int grow = qt * 128 + w * 32 + row;
            size_t base = (size_t)(b * L_ + grow) * D_ + h * DH_ + l31;
            Ow[base]      = (bf16_t)(acc0[reg] * inv);
            Ow[base + 32] = (bf16_t)(acc1[reg] * inv);
        }
        // pass-1 staging is safe: every wave passed the loop's final
        // __syncthreads after its last LDS read; stores above are global-only.
    }
}

extern "C" void kernel_launch(void* const* d_in, const int* in_sizes, int n_in,
                              void* d_out, int out_size, void* d_ws, size_t ws_size,
                              hipStream_t stream)
{
    // Inputs fp32, output fp32. Compute in bf16 MFMA, final store fp32.
    const float* queries = (const float*)d_in[0];
    const float* keys    = (const float*)d_in[1];
    const float* values  = (const float*)d_in[2];
    const float* Wq = (const float*)d_in[3];
    const float* Wk = (const float*)d_in[4];
    const float* Wv = (const float*)d_in[5];
    const float* Wo = (const float*)d_in[6];
    float* out = (float*)d_out;

    const size_t SZ = (size_t)B_ * L_ * D_;   // 8,388,608
    const size_t WZ = (size_t)D_ * D_;        // 1,048,576
    bf16_t* cbuf  = (bf16_t*)d_ws;            // queries bf16; later Vt
    bf16_t* cWq   = cbuf + SZ;
    bf16_t* cWk   = cWq + WZ;
    bf16_t* cWv   = cWk + WZ;
    bf16_t* cWo   = cWv + WZ;
    bf16_t* q_ws  = cWo + WZ;
    bf16_t* k_ws  = q_ws + SZ;
    bf16_t* vt_ws = k_ws + SZ;                // V row-major; later attn out

    // keys/values bf16 scratch carved from d_out (dead until final GEMM).
    bf16_t* ck = (bf16_t*)d_out;
    bf16_t* cv = ck + SZ;

    cvt_all<<<28672, 256, 0, stream>>>(queries, keys, values, Wq, Wk, Wv, Wo,
                                       cbuf, ck, cv, cWq, cWk, cWv, cWo);

    // QKV projections; all row-major outputs (q_ws, k_ws, vt_ws=V rowmajor)
    gemm_qkv<<<dim3(8, 64, 3), 256, 0, stream>>>(
        cbuf, cWq, q_ws,
        ck,   cWk, k_ws,
        cv,   cWv, vt_ws);

    // V [B*L][1024] -> Vt[B][H][64][2048] into cbuf (queries-bf16 now dead)
    transpose_v<<<dim3(32, H_, B_), 256, 0, stream>>>(vt_ws, cbuf);

    // attn reads Vt from cbuf, writes output into vt_ws (V rowmajor now dead)
    attn_fwd<<<dim3(8, H_, B_), 256, 0, stream>>>(q_ws, k_ws, cbuf, vt_ws);

    gemm_bt<<<dim3(8, 64), 256, 0, stream>>>(vt_ws, cWo, nullptr, out, 2);
}